// Round 1
// baseline (2547.116 us; speedup 1.0000x reference)
//
#include <hip/hip_runtime.h>
#include <math.h>

#define NTOK 4096
#define DMODEL 2048
#define ENUM 64
#define HSH 8192
#define BND 512
#define FEXP 1024
#define MAXL 304   // (16384/64/8 + 6)*8

typedef float f32x4 __attribute__((ext_vector_type(4)));
using bf16x8 = __attribute__((ext_vector_type(8))) __bf16;

__device__ __forceinline__ unsigned short f2bf(float f) {
    union { float f; unsigned int u; } v; v.f = f;
    unsigned int u = v.u;
    return (unsigned short)((u + 0x7FFFu + ((u >> 16) & 1u)) >> 16);
}
__device__ __forceinline__ float bf2f(unsigned short s) {
    union { unsigned int u; float f; } v; v.u = ((unsigned int)s) << 16;
    return v.f;
}

// ---------------- init ----------------
__global__ __launch_bounds__(256) void init_kernel(float* zacc, int* slot2tok) {
    int i = blockIdx.x * 256 + threadIdx.x;
    if (i == 0) *zacc = 0.f;
    if (i < ENUM * MAXL) slot2tok[i] = NTOK;  // sentinel = zero row
}

// ---------------- router: fp32 logits, top-4, gating, z_loss ----------------
__global__ __launch_bounds__(256) void router_kernel(
    const float* __restrict__ x, const float* __restrict__ rw,
    const float* __restrict__ bias, int* __restrict__ topk_idx,
    float* __restrict__ gating, float* __restrict__ zacc)
{
    int n = blockIdx.x;
    __shared__ float hrow[DMODEL];
    __shared__ float partial[ENUM][4];
    const float* hx = x + (size_t)n * DMODEL;
    for (int i = threadIdx.x; i < DMODEL; i += 256) hrow[i] = hx[i];
    __syncthreads();
    int e = threadIdx.x & 63;
    int p = threadIdx.x >> 6;
    const float4* wr4 = (const float4*)(rw + (size_t)e * DMODEL + p * 512);
    const float4* h4 = (const float4*)(hrow + p * 512);
    float s = 0.f;
    for (int i = 0; i < 128; i++) {
        float4 a = h4[i]; float4 b = wr4[i];
        s += a.x * b.x + a.y * b.y + a.z * b.z + a.w * b.w;
    }
    partial[e][p] = s;
    __syncthreads();
    if (threadIdx.x < 64) {  // wave 0, lane == expert
        float logit = partial[e][0] + partial[e][1] + partial[e][2] + partial[e][3];
        float sel = 1.f / (1.f + expf(-logit)) + bias[e];
        float zsq = logit * logit;
        for (int off = 32; off; off >>= 1) zsq += __shfl_down(zsq, off);
        if (e == 0) atomicAdd(zacc, zsq);
        float cur = sel;
        float ch_logit[4]; int ch_idx[4];
        for (int kk = 0; kk < 4; kk++) {
            float v = cur; int idx = e;
            for (int off = 1; off < 64; off <<= 1) {
                float v2 = __shfl_xor(v, off);
                int i2 = __shfl_xor(idx, off);
                if (v2 > v || (v2 == v && i2 < idx)) { v = v2; idx = i2; }
            }
            ch_idx[kk] = idx;
            ch_logit[kk] = __shfl(logit, idx);
            if (e == idx) cur = -1e30f;
        }
        if (e == 0) {
            float mx = ch_logit[0];
            for (int kk = 1; kk < 4; kk++) mx = fmaxf(mx, ch_logit[kk]);
            float se = 0.f, ex[4];
            for (int kk = 0; kk < 4; kk++) { ex[kk] = expf(ch_logit[kk] - mx); se += ex[kk]; }
            for (int kk = 0; kk < 4; kk++) {
                topk_idx[n * 4 + kk] = ch_idx[kk];
                gating[n * 4 + kk] = ex[kk] / se;
            }
        }
    }
}

// ---------------- stable per-expert ranks (replicates stable argsort) ----------------
__global__ __launch_bounds__(256) void rank_kernel(
    const int* __restrict__ topk_idx, int* __restrict__ slot2tok, int* __restrict__ gmap)
{
    int e = blockIdx.x;
    __shared__ int wsum[4];
    int tid = threadIdx.x;
    int lane = tid & 63, w = tid >> 6;
    int running = 0;
    for (int c = 0; c < NTOK * 4; c += 256) {
        int i = c + tid;
        int fl = topk_idx[i];
        bool m = (fl == e);
        unsigned long long bal = __ballot(m);
        int prefix = __popcll(bal & ((1ULL << lane) - 1ULL));
        if (lane == 0) wsum[w] = __popcll(bal);
        __syncthreads();
        int wbase = 0;
        for (int j = 0; j < w; j++) wbase += wsum[j];
        int total = wsum[0] + wsum[1] + wsum[2] + wsum[3];
        if (m) {
            int rank = running + wbase + prefix;
            int tok = i >> 2;
            if (rank < MAXL) {
                slot2tok[e * MAXL + rank] = tok;
                gmap[i] = e * MAXL + rank;
            } else gmap[i] = -1;
        }
        running += total;
        __syncthreads();
    }
}

// ---------------- generic MFMA GEMM ----------------
// AMODE: 0 = fp32 A (convert), 1 = bf16 A, 2 = gathered bf16 A via slot2tok
// BNN:   0 = B is [n][k] fp32 (B^T layout), 1 = B is [k][n] fp32 (transpose into LDS)
// DUAL:  second B matrix (for silu(c1)*c2 epilogue)
// EPI:   0 = store bf16, 1 = silu(c1)*c2 -> bf16, 2 = store f32, 3 = f32 (prev+c)*0.5
template<int AMODE, int BNN, int DUAL, int EPI, int BN>
__global__ __launch_bounds__(256) void gemm_kernel(
    const void* __restrict__ Ab, long long aZ, int lda,
    const int* __restrict__ gtab,
    const float* __restrict__ B1b, const float* __restrict__ B2b, long long bZ, int ldb,
    void* __restrict__ Cb, long long cZ, int ldc,
    int M, int K)
{
    constexpr int BM = 128, BK = 64;
    constexpr int PITCH = BK + 8;            // +16B pad: 2-way-max LDS conflicts
    constexpr int WN = BN / 2;
    constexpr int NB = WN / 16;
    __shared__ unsigned short As[BM][PITCH];
    __shared__ unsigned short Bs[DUAL ? 2 : 1][BN][PITCH];

    const int z = blockIdx.z;
    const int m0 = blockIdx.y * BM;
    const int n0 = blockIdx.x * BN;
    const int tid = threadIdx.x;
    const int lane = tid & 63;
    const int w = tid >> 6;
    const int wm = (w >> 1) * 64;
    const int wn = (w & 1) * WN;
    const int lrow = lane & 15;
    const int lkb = (lane >> 4) * 8;

    const float* B1 = B1b + (size_t)z * bZ;
    const float* B2 = DUAL ? (B2b + (size_t)z * bZ) : nullptr;
    const int* gt = nullptr;
    if constexpr (AMODE == 2) gt = gtab + (size_t)z * MAXL;

    f32x4 acc[4][NB];
    f32x4 acc2[DUAL ? 4 : 1][DUAL ? NB : 1];
    for (int a = 0; a < 4; a++)
        for (int b = 0; b < NB; b++) {
            acc[a][b] = (f32x4)0.f;
            if constexpr (DUAL) acc2[a][b] = (f32x4)0.f;
        }

    for (int k0 = 0; k0 < K; k0 += BK) {
        // ---- stage A (128 x 64) ----
#pragma unroll
        for (int i = 0; i < 8; i++) {
            int idx = i * 256 + tid;
            int r = idx >> 4, c4 = (idx & 15) * 4;
            int m = m0 + r;
            unsigned int p0 = 0, p1 = 0;
            if constexpr (AMODE == 0) {
                if (m < M) {
                    const float* ap = (const float*)Ab + (size_t)z * aZ + (size_t)m * lda + k0 + c4;
                    float4 f = *(const float4*)ap;
                    p0 = f2bf(f.x) | ((unsigned)f2bf(f.y) << 16);
                    p1 = f2bf(f.z) | ((unsigned)f2bf(f.w) << 16);
                }
            } else if constexpr (AMODE == 1) {
                if (m < M) {
                    const unsigned short* ap = (const unsigned short*)Ab + (size_t)z * aZ + (size_t)m * lda + k0 + c4;
                    uint2 v = *(const uint2*)ap;
                    p0 = v.x; p1 = v.y;
                }
            } else {
                int tok = (m < M) ? gt[m] : NTOK;
                if (tok < NTOK) {
                    const unsigned short* ap = (const unsigned short*)Ab + (size_t)tok * lda + k0 + c4;
                    uint2 v = *(const uint2*)ap;
                    p0 = v.x; p1 = v.y;
                }
            }
            uint2 pk; pk.x = p0; pk.y = p1;
            *(uint2*)&As[r][c4] = pk;
        }
        // ---- stage B ----
        if constexpr (BNN == 0) {
#pragma unroll
            for (int bsel = 0; bsel < (DUAL ? 2 : 1); bsel++) {
                const float* Bp = bsel ? B2 : B1;
#pragma unroll
                for (int i = 0; i < BN / 16; i++) {
                    int idx = i * 256 + tid;
                    int r = idx >> 4, c4 = (idx & 15) * 4;
                    const float* bp = Bp + (size_t)(n0 + r) * ldb + k0 + c4;
                    float4 f = *(const float4*)bp;
                    uint2 pk;
                    pk.x = f2bf(f.x) | ((unsigned)f2bf(f.y) << 16);
                    pk.y = f2bf(f.z) | ((unsigned)f2bf(f.w) << 16);
                    *(uint2*)&Bs[bsel][r][c4] = pk;
                }
            }
        } else {
            constexpr int GPR = BN / 4;
#pragma unroll
            for (int bsel = 0; bsel < (DUAL ? 2 : 1); bsel++) {
                const float* Bp = bsel ? B2 : B1;
#pragma unroll
                for (int i = 0; i < BN / 16; i++) {
                    int idx = i * 256 + tid;
                    int rk = idx / GPR, n4 = (idx % GPR) * 4;
                    const float* bp = Bp + (size_t)(k0 + rk) * ldb + n0 + n4;
                    float4 f = *(const float4*)bp;
                    Bs[bsel][n4 + 0][rk] = f2bf(f.x);
                    Bs[bsel][n4 + 1][rk] = f2bf(f.y);
                    Bs[bsel][n4 + 2][rk] = f2bf(f.z);
                    Bs[bsel][n4 + 3][rk] = f2bf(f.w);
                }
            }
        }
        __syncthreads();
        // ---- compute: 2 K-substeps of 32 ----
#pragma unroll
        for (int ks = 0; ks < 2; ks++) {
            int kc = ks * 32 + lkb;
            bf16x8 a[4];
#pragma unroll
            for (int mi = 0; mi < 4; mi++)
                a[mi] = *(const bf16x8*)&As[wm + mi * 16 + lrow][kc];
#pragma unroll
            for (int ni = 0; ni < NB; ni++) {
                bf16x8 b = *(const bf16x8*)&Bs[0][wn + ni * 16 + lrow][kc];
#pragma unroll
                for (int mi = 0; mi < 4; mi++)
                    acc[mi][ni] = __builtin_amdgcn_mfma_f32_16x16x32_bf16(a[mi], b, acc[mi][ni], 0, 0, 0);
            }
            if constexpr (DUAL) {
#pragma unroll
                for (int ni = 0; ni < NB; ni++) {
                    bf16x8 b = *(const bf16x8*)&Bs[1][wn + ni * 16 + lrow][kc];
#pragma unroll
                    for (int mi = 0; mi < 4; mi++)
                        acc2[mi][ni] = __builtin_amdgcn_mfma_f32_16x16x32_bf16(a[mi], b, acc2[mi][ni], 0, 0, 0);
                }
            }
        }
        __syncthreads();
    }
    // ---- epilogue: C/D layout col=lane&15, row=(lane>>4)*4+reg ----
    const int rb0 = m0 + wm + ((lane >> 4) << 2);
#pragma unroll
    for (int mi = 0; mi < 4; mi++) {
#pragma unroll
        for (int ni = 0; ni < NB; ni++) {
            int col = n0 + wn + ni * 16 + lrow;
#pragma unroll
            for (int r = 0; r < 4; r++) {
                int row = rb0 + mi * 16 + r;
                if (row < M) {
                    size_t ci = (size_t)z * cZ + (size_t)row * ldc + col;
                    float v = acc[mi][ni][r];
                    if constexpr (EPI == 0) {
                        ((unsigned short*)Cb)[ci] = f2bf(v);
                    } else if constexpr (EPI == 1) {
                        float u = acc2[mi][ni][r];
                        float s = v / (1.f + expf(-v)) * u;
                        ((unsigned short*)Cb)[ci] = f2bf(s);
                    } else if constexpr (EPI == 2) {
                        ((float*)Cb)[ci] = v;
                    } else {
                        float* cp = (float*)Cb + ci;
                        *cp = (*cp + v) * 0.5f;
                    }
                }
            }
        }
    }
}

// ---------------- gather + gating combine: routed_b = sum_k g * pout[slot] ----------------
__global__ __launch_bounds__(256) void gather_kernel(
    const unsigned short* __restrict__ pout, const int* __restrict__ gmap,
    const float* __restrict__ gating, unsigned short* __restrict__ routed_b)
{
    int n = blockIdx.x;
    int j = threadIdx.x * 2;
    float a0 = 0.f, a1 = 0.f;
#pragma unroll
    for (int kk = 0; kk < 4; kk++) {
        int slot = gmap[n * 4 + kk];
        float g = gating[n * 4 + kk];
        if (slot >= 0) {
            const unsigned short* pr = pout + (size_t)slot * BND + j;
            a0 += g * bf2f(pr[0]);
            a1 += g * bf2f(pr[1]);
        }
    }
    routed_b[(size_t)n * BND + j] = f2bf(a0);
    routed_b[(size_t)n * BND + j + 1] = f2bf(a1);
}

__global__ void zloss_kernel(const float* zacc, float* out) {
    out[0] = zacc[0] * (1.0e-4f / (float)(NTOK * ENUM));
}

// ---------------- host ----------------
extern "C" void kernel_launch(void* const* d_in, const int* in_sizes, int n_in,
                              void* d_out, int out_size, void* d_ws, size_t ws_size,
                              hipStream_t stream)
{
    const float* x      = (const float*)d_in[0];
    const float* ebias  = (const float*)d_in[1];
    const float* rw     = (const float*)d_in[2];
    const float* gate_w = (const float*)d_in[3];
    const float* up_w   = (const float*)d_in[4];
    const float* down_w = (const float*)d_in[5];
    const float* w_down = (const float*)d_in[6];
    const float* w_up   = (const float*)d_in[7];
    const float* w12    = (const float*)d_in[8];
    const float* w3     = (const float*)d_in[9];
    float* out = (float*)d_out;

    // chunking: small-ws mode processes rows/experts in 4 chunks
    int nch = (ws_size >= (size_t)150 * 1024 * 1024) ? 1 : 4;
    int rows_per = NTOK / nch;
    int exp_per = ENUM / nch;

    char* ws = (char*)d_ws;
    size_t off = 0;
    auto alloc = [&](size_t b) { size_t o = off; off += (b + 255) & ~(size_t)255; return o; };
    float* zacc     = (float*)(ws + alloc(4));
    int*   topk     = (int*)(ws + alloc((size_t)NTOK * 4 * 4));
    float* gating   = (float*)(ws + alloc((size_t)NTOK * 4 * 4));
    int*   gmap     = (int*)(ws + alloc((size_t)NTOK * 4 * 4));
    int*   slot2tok = (int*)(ws + alloc((size_t)ENUM * MAXL * 4));
    unsigned short* hd   = (unsigned short*)(ws + alloc((size_t)NTOK * BND * 2));
    unsigned short* pout = (unsigned short*)(ws + alloc((size_t)ENUM * MAXL * BND * 2));
    unsigned short* act  = (unsigned short*)(ws + alloc((size_t)exp_per * MAXL * FEXP * 2));
    unsigned short* Hbuf = (unsigned short*)(ws + alloc((size_t)rows_per * HSH * 2));
    unsigned short* rb   = (unsigned short*)(ws + alloc((size_t)NTOK * BND * 2));

    init_kernel<<<(ENUM * MAXL + 255) / 256, 256, 0, stream>>>(zacc, slot2tok);
    router_kernel<<<NTOK, 256, 0, stream>>>(x, rw, ebias, topk, gating, zacc);
    rank_kernel<<<ENUM, 256, 0, stream>>>(topk, slot2tok, gmap);

    // hd = x @ w_down^T -> bf16 [4096][512]
    gemm_kernel<0, 0, 0, 0, 128><<<dim3(BND / 128, NTOK / 128, 1), 256, 0, stream>>>(
        x, 0, DMODEL, nullptr, w_down, nullptr, 0, DMODEL, hd, 0, BND, NTOK, DMODEL);

    // shared MLP
    for (int c = 0; c < nch; c++) {
        gemm_kernel<0, 0, 1, 1, 64><<<dim3(HSH / 64, rows_per / 128, 1), 256, 0, stream>>>(
            x + (size_t)c * rows_per * DMODEL, 0, DMODEL, nullptr, gate_w, up_w, 0, DMODEL,
            Hbuf, 0, HSH, rows_per, DMODEL);
        gemm_kernel<1, 0, 0, 2, 128><<<dim3(DMODEL / 128, rows_per / 128, 1), 256, 0, stream>>>(
            Hbuf, 0, HSH, nullptr, down_w, nullptr, 0, HSH,
            out + (size_t)c * rows_per * DMODEL, 0, DMODEL, rows_per, HSH);
    }

    // expert path
    for (int c = 0; c < nch; c++) {
        gemm_kernel<2, 1, 1, 1, 64><<<dim3(FEXP / 64, 3, exp_per), 256, 0, stream>>>(
            hd, 0, BND, slot2tok + (size_t)c * exp_per * MAXL,
            w12 + (size_t)c * exp_per * BND * 2048, w12 + (size_t)c * exp_per * BND * 2048 + 1024,
            (long long)BND * 2048, 2048, act, (long long)MAXL * FEXP, FEXP, MAXL, BND);
        gemm_kernel<1, 1, 0, 0, 128><<<dim3(BND / 128, 3, exp_per), 256, 0, stream>>>(
            act, (long long)MAXL * FEXP, FEXP, nullptr,
            w3 + (size_t)c * exp_per * FEXP * BND, nullptr,
            (long long)FEXP * BND, BND, pout + (size_t)c * exp_per * MAXL * BND,
            (long long)MAXL * BND, BND, MAXL, FEXP);
    }

    gather_kernel<<<NTOK, 256, 0, stream>>>(pout, gmap, gating, rb);

    // routed = routed_b @ w_up^T ; out = (shared + routed) * 0.5
    gemm_kernel<1, 0, 0, 3, 128><<<dim3(DMODEL / 128, NTOK / 128, 1), 256, 0, stream>>>(
        rb, 0, BND, nullptr, w_up, nullptr, 0, BND, out, 0, DMODEL, NTOK, BND);

    zloss_kernel<<<1, 1, 0, stream>>>(zacc, out + (size_t)NTOK * DMODEL);
}

// Round 3
// 1341.488 us; speedup vs baseline: 1.8987x; 1.8987x over previous
//
#include <hip/hip_runtime.h>
#include <math.h>

#define NTOK 4096
#define DMODEL 2048
#define ENUM 64
#define HSH 8192
#define BND 512
#define FEXP 1024
#define MAXL 304   // (16384/64/8 + 6)*8
#define EPAD 384   // padded expert rows (3*128)
#define ECH 16     // experts per chunk

typedef float f32x4 __attribute__((ext_vector_type(4)));
using bf16x8 = __attribute__((ext_vector_type(8))) __bf16;

typedef const __attribute__((address_space(1))) unsigned int cgu32;
typedef __attribute__((address_space(3))) unsigned int lu32;
#define GLOAD16(g, l) __builtin_amdgcn_global_load_lds((cgu32*)(g), (lu32*)(l), 16, 0, 0)

__device__ __forceinline__ unsigned short f2bf(float f) {
    union { float f; unsigned int u; } v; v.f = f;
    unsigned int u = v.u;
    return (unsigned short)((u + 0x7FFFu + ((u >> 16) & 1u)) >> 16);
}
__device__ __forceinline__ float bf2f(unsigned short s) {
    union { unsigned int u; float f; } v; v.u = ((unsigned int)s) << 16;
    return v.f;
}

// ---------------- init ----------------
__global__ __launch_bounds__(256) void init_kernel(float* zacc, int* slot2tok, unsigned short* hdz) {
    int i = blockIdx.x * 256 + threadIdx.x;
    if (i == 0) *zacc = 0.f;
    if (i < ENUM * MAXL) slot2tok[i] = NTOK;  // sentinel -> zero row of hd
    if (i < BND) hdz[i] = 0;                  // hd row NTOK = zeros
}

// ---------------- fp32 -> bf16 convert ----------------
__global__ __launch_bounds__(256) void convert_kernel(
    const float* __restrict__ in, unsigned short* __restrict__ out, long long n)
{
    long long stride = (long long)gridDim.x * 256 * 8;
    for (long long i = ((long long)blockIdx.x * 256 + threadIdx.x) * 8; i < n; i += stride) {
        float4 a = *(const float4*)(in + i);
        float4 b = *(const float4*)(in + i + 4);
        union { unsigned short s[8]; uint4 v; } o;
        o.s[0] = f2bf(a.x); o.s[1] = f2bf(a.y); o.s[2] = f2bf(a.z); o.s[3] = f2bf(a.w);
        o.s[4] = f2bf(b.x); o.s[5] = f2bf(b.y); o.s[6] = f2bf(b.z); o.s[7] = f2bf(b.w);
        *(uint4*)(out + i) = o.v;
    }
}

// ---------------- transpose-convert: in [K][N] fp32 -> out [N][K] bf16 (per z) ----------------
__global__ __launch_bounds__(256) void tconv_kernel(
    const float* __restrict__ in, unsigned short* __restrict__ out, int Kd, int Nd)
{
    __shared__ float t[32][33];
    size_t zoff = (size_t)blockIdx.z * Kd * Nd;
    in += zoff; out += zoff;
    int n0 = blockIdx.x * 32, k0 = blockIdx.y * 32;
    int r = threadIdx.x >> 3, c = (threadIdx.x & 7) * 4;
    float4 v = *(const float4*)(in + (size_t)(k0 + r) * Nd + n0 + c);
    t[r][c] = v.x; t[r][c + 1] = v.y; t[r][c + 2] = v.z; t[r][c + 3] = v.w;
    __syncthreads();
    ushort4 o;
    o.x = f2bf(t[c + 0][r]); o.y = f2bf(t[c + 1][r]);
    o.z = f2bf(t[c + 2][r]); o.w = f2bf(t[c + 3][r]);
    *(ushort4*)(out + (size_t)(n0 + r) * Kd + k0 + c) = o;
}

// ---------------- router: fp32 logits, top-4, gating, z_loss ----------------
__global__ __launch_bounds__(256) void router_kernel(
    const float* __restrict__ x, const float* __restrict__ rw,
    const float* __restrict__ bias, int* __restrict__ topk_idx,
    float* __restrict__ gating, float* __restrict__ zacc)
{
    int n = blockIdx.x;
    __shared__ float hrow[DMODEL];
    __shared__ float partial[ENUM][4];
    const float* hx = x + (size_t)n * DMODEL;
    for (int i = threadIdx.x; i < DMODEL; i += 256) hrow[i] = hx[i];
    __syncthreads();
    int e = threadIdx.x & 63;
    int p = threadIdx.x >> 6;
    const float4* wr4 = (const float4*)(rw + (size_t)e * DMODEL + p * 512);
    const float4* h4 = (const float4*)(hrow + p * 512);
    float s = 0.f;
    for (int i = 0; i < 128; i++) {
        float4 a = h4[i]; float4 b = wr4[i];
        s += a.x * b.x + a.y * b.y + a.z * b.z + a.w * b.w;
    }
    partial[e][p] = s;
    __syncthreads();
    if (threadIdx.x < 64) {
        float logit = partial[e][0] + partial[e][1] + partial[e][2] + partial[e][3];
        float sel = 1.f / (1.f + expf(-logit)) + bias[e];
        float zsq = logit * logit;
        for (int off = 32; off; off >>= 1) zsq += __shfl_down(zsq, off);
        if (e == 0) atomicAdd(zacc, zsq);
        float cur = sel;
        float ch_logit[4]; int ch_idx[4];
        for (int kk = 0; kk < 4; kk++) {
            float v = cur; int idx = e;
            for (int off = 1; off < 64; off <<= 1) {
                float v2 = __shfl_xor(v, off);
                int i2 = __shfl_xor(idx, off);
                if (v2 > v || (v2 == v && i2 < idx)) { v = v2; idx = i2; }
            }
            ch_idx[kk] = idx;
            ch_logit[kk] = __shfl(logit, idx);
            if (e == idx) cur = -1e30f;
        }
        if (e == 0) {
            float mx = ch_logit[0];
            for (int kk = 1; kk < 4; kk++) mx = fmaxf(mx, ch_logit[kk]);
            float se = 0.f, ex[4];
            for (int kk = 0; kk < 4; kk++) { ex[kk] = expf(ch_logit[kk] - mx); se += ex[kk]; }
            for (int kk = 0; kk < 4; kk++) {
                topk_idx[n * 4 + kk] = ch_idx[kk];
                gating[n * 4 + kk] = ex[kk] / se;
            }
        }
    }
}

// ---------------- stable per-expert ranks ----------------
__global__ __launch_bounds__(256) void rank_kernel(
    const int* __restrict__ topk_idx, int* __restrict__ slot2tok, int* __restrict__ gmap)
{
    int e = blockIdx.x;
    __shared__ int wsum[4];
    int tid = threadIdx.x;
    int lane = tid & 63, w = tid >> 6;
    int running = 0;
    for (int c = 0; c < NTOK * 4; c += 256) {
        int i = c + tid;
        int fl = topk_idx[i];
        bool m = (fl == e);
        unsigned long long bal = __ballot(m);
        int prefix = __popcll(bal & ((1ULL << lane) - 1ULL));
        if (lane == 0) wsum[w] = __popcll(bal);
        __syncthreads();
        int wbase = 0;
        for (int j = 0; j < w; j++) wbase += wsum[j];
        int total = wsum[0] + wsum[1] + wsum[2] + wsum[3];
        if (m) {
            int rank = running + wbase + prefix;
            int tok = i >> 2;
            if (rank < MAXL) {
                slot2tok[e * MAXL + rank] = tok;
                gmap[i] = e * MAXL + rank;
            } else gmap[i] = -1;
        }
        running += total;
        __syncthreads();
    }
}

// ---------------- m97-structure bf16 GEMM ----------------
// C[M][N](z) = A[M][K](z) * B[N][K](z)^T ; 128x128x64 tile, 4 waves, gload_lds + XOR swizzle
// GATHER: A row r -> hd[slot2tok[z*MAXL+r]] (sentinel NTOK = zero row)
// EPI: 0 = store bf16 ; 1 = C = silu(C)*acc bf16 (in-place RMW) ; 2 = store f32 ; 3 = f32 (prev+acc)*0.5
template<int GATHER, int EPI>
__global__ __launch_bounds__(256) void gemm2(
    const unsigned short* __restrict__ A, long long aZ, int lda,
    const int* __restrict__ gtab,
    const unsigned short* __restrict__ Bm, long long bZ, int ldb,
    void* __restrict__ Cb, long long cZ, int ldc,
    int M, int K)
{
    __shared__ unsigned short As[128 * 64];
    __shared__ unsigned short Bs[128 * 64];
    const int z = blockIdx.z;
    const int m0 = blockIdx.y * 128;
    const int n0 = blockIdx.x * 128;
    const int tid = threadIdx.x;
    const int lane = tid & 63;
    const int w = tid >> 6;
    const int wm = (w >> 1) * 64;
    const int wn = (w & 1) * 64;

    const unsigned short* Ab = A + (GATHER ? (size_t)0 : (size_t)z * aZ);
    const unsigned short* Bb = Bm + (size_t)z * bZ;

    // staging: 4 units x 16B per thread per tile; LDS dest linear, source pre-swizzled
    size_t asrc[4], bsrc[4];
    int ldso[4];
#pragma unroll
    for (int i = 0; i < 4; i++) {
        int u = i * 256 + tid;
        int r = u >> 3;                       // tile row 0..127
        int ce = ((u & 7) ^ (r & 7)) * 8;     // swizzled element col (0..56)
        ldso[i] = u * 8;
        if constexpr (GATHER) {
            int mr = m0 + r;
            int tok = (mr < M) ? gtab[(size_t)z * MAXL + mr] : NTOK;
            asrc[i] = (size_t)tok * lda + ce;
        } else {
            asrc[i] = (size_t)(m0 + r) * lda + ce;
        }
        bsrc[i] = (size_t)(n0 + r) * ldb + ce;
    }

    const int lrow = lane & 15;
    const int kg = lane >> 4;
    const int mk = (lrow & 7) << 4;           // row-XOR mask (bytes)
    int arx[4], brx[4];
#pragma unroll
    for (int t = 0; t < 4; t++) {
        arx[t] = (wm + t * 16 + lrow) * 128;
        brx[t] = (wn + t * 16 + lrow) * 128;
    }

    f32x4 acc[4][4];
#pragma unroll
    for (int a = 0; a < 4; a++)
#pragma unroll
        for (int b = 0; b < 4; b++) acc[a][b] = (f32x4)0.f;

    for (int k0 = 0; k0 < K; k0 += 64) {
#pragma unroll
        for (int i = 0; i < 4; i++) GLOAD16(Ab + asrc[i] + k0, &As[ldso[i]]);
#pragma unroll
        for (int i = 0; i < 4; i++) GLOAD16(Bb + bsrc[i] + k0, &Bs[ldso[i]]);
        __syncthreads();
#pragma unroll
        for (int ks = 0; ks < 2; ks++) {
            const int cb = (ks * 64 + kg * 16) ^ mk;
            bf16x8 a[4], b[4];
#pragma unroll
            for (int t = 0; t < 4; t++) {
                a[t] = *(const bf16x8*)((const char*)As + arx[t] + cb);
                b[t] = *(const bf16x8*)((const char*)Bs + brx[t] + cb);
            }
#pragma unroll
            for (int ni = 0; ni < 4; ni++)
#pragma unroll
                for (int mi = 0; mi < 4; mi++)
                    acc[mi][ni] = __builtin_amdgcn_mfma_f32_16x16x32_bf16(a[mi], b[ni], acc[mi][ni], 0, 0, 0);
        }
        __syncthreads();
    }

    const int rb0 = m0 + wm + (kg << 2);
#pragma unroll
    for (int mi = 0; mi < 4; mi++)
#pragma unroll
        for (int ni = 0; ni < 4; ni++) {
            int col = n0 + wn + ni * 16 + lrow;
#pragma unroll
            for (int r = 0; r < 4; r++) {
                int row = rb0 + mi * 16 + r;
                if (row < M) {
                    size_t ci = (size_t)z * cZ + (size_t)row * ldc + col;
                    float v = acc[mi][ni][r];
                    if constexpr (EPI == 0) {
                        ((unsigned short*)Cb)[ci] = f2bf(v);
                    } else if constexpr (EPI == 1) {
                        unsigned short* cp = (unsigned short*)Cb + ci;
                        float g = bf2f(*cp);
                        *cp = f2bf(g / (1.f + expf(-g)) * v);
                    } else if constexpr (EPI == 2) {
                        ((float*)Cb)[ci] = v;
                    } else {
                        float* cp = (float*)Cb + ci;
                        *cp = (*cp + v) * 0.5f;
                    }
                }
            }
        }
}

// ---------------- silu-mul: act = silu(h12[:,:1024]) * h12[:,1024:] ----------------
__global__ __launch_bounds__(256) void siluact_kernel(
    const unsigned short* __restrict__ h12, unsigned short* __restrict__ act)
{
    int e = blockIdx.y, m = blockIdx.x;
    const unsigned short* hr = h12 + ((size_t)e * EPAD + m) * 2048;
    unsigned short* ar = act + ((size_t)e * EPAD + m) * 1024;
    int j = threadIdx.x * 4;
    ushort4 h1 = *(const ushort4*)(hr + j);
    ushort4 h2 = *(const ushort4*)(hr + 1024 + j);
    ushort4 o;
    float v;
    v = bf2f(h1.x); o.x = f2bf(v / (1.f + expf(-v)) * bf2f(h2.x));
    v = bf2f(h1.y); o.y = f2bf(v / (1.f + expf(-v)) * bf2f(h2.y));
    v = bf2f(h1.z); o.z = f2bf(v / (1.f + expf(-v)) * bf2f(h2.z));
    v = bf2f(h1.w); o.w = f2bf(v / (1.f + expf(-v)) * bf2f(h2.w));
    *(ushort4*)(ar + j) = o;
}

// ---------------- gather + gating combine ----------------
__global__ __launch_bounds__(256) void gather_kernel(
    const unsigned short* __restrict__ pout, const int* __restrict__ gmap,
    const float* __restrict__ gating, unsigned short* __restrict__ routed_b)
{
    int n = blockIdx.x;
    int j = threadIdx.x * 2;
    float a0 = 0.f, a1 = 0.f;
#pragma unroll
    for (int kk = 0; kk < 4; kk++) {
        int slot = gmap[n * 4 + kk];
        float g = gating[n * 4 + kk];
        if (slot >= 0) {
            const unsigned short* pr = pout + (size_t)slot * BND + j;
            a0 += g * bf2f(pr[0]);
            a1 += g * bf2f(pr[1]);
        }
    }
    routed_b[(size_t)n * BND + j] = f2bf(a0);
    routed_b[(size_t)n * BND + j + 1] = f2bf(a1);
}

__global__ void zloss_kernel(const float* zacc, float* out) {
    out[0] = zacc[0] * (1.0e-4f / (float)(NTOK * ENUM));
}

// ---------------- host ----------------
extern "C" void kernel_launch(void* const* d_in, const int* in_sizes, int n_in,
                              void* d_out, int out_size, void* d_ws, size_t ws_size,
                              hipStream_t stream)
{
    const float* x      = (const float*)d_in[0];
    const float* ebias  = (const float*)d_in[1];
    const float* rw     = (const float*)d_in[2];
    const float* gate_w = (const float*)d_in[3];
    const float* up_w   = (const float*)d_in[4];
    const float* down_w = (const float*)d_in[5];
    const float* w_down = (const float*)d_in[6];
    const float* w_up   = (const float*)d_in[7];
    const float* w12    = (const float*)d_in[8];
    const float* w3     = (const float*)d_in[9];
    float* out = (float*)d_out;

    char* ws = (char*)d_ws;
    size_t off = 0;
    auto alloc = [&](size_t b) { size_t o = off; off += (b + 255) & ~(size_t)255; return o; };
    float* zacc     = (float*)(ws + alloc(4));
    int*   topk     = (int*)(ws + alloc((size_t)NTOK * 4 * 4));
    float* gating   = (float*)(ws + alloc((size_t)NTOK * 4 * 4));
    int*   gmap     = (int*)(ws + alloc((size_t)NTOK * 4 * 4));
    int*   slot2tok = (int*)(ws + alloc((size_t)ENUM * MAXL * 4));
    unsigned short* xb     = (unsigned short*)(ws + alloc((size_t)NTOK * DMODEL * 2));
    unsigned short* hd     = (unsigned short*)(ws + alloc((size_t)(NTOK + 1) * BND * 2));
    unsigned short* rb     = (unsigned short*)(ws + alloc((size_t)NTOK * BND * 2));
    unsigned short* wdownb = (unsigned short*)(ws + alloc((size_t)BND * DMODEL * 2));
    unsigned short* wupb   = (unsigned short*)(ws + alloc((size_t)DMODEL * BND * 2));
    unsigned short* wbuf   = (unsigned short*)(ws + alloc((size_t)HSH * DMODEL * 2)); // 33.55MB (FIXED: was /2)
    unsigned short* H1     = (unsigned short*)(ws + alloc((size_t)NTOK * HSH * 2));   // 67.1MB arena
    // expert-phase aliases inside H1 arena:
    unsigned short* h12  = H1;
    unsigned short* act  = H1 + (size_t)ECH * EPAD * 2048;
    unsigned short* pout = H1 + (size_t)ECH * EPAD * 2048 + (size_t)ECH * EPAD * 1024;

    init_kernel<<<(ENUM * MAXL + 255) / 256, 256, 0, stream>>>(zacc, slot2tok, hd + (size_t)NTOK * BND);
    router_kernel<<<NTOK, 256, 0, stream>>>(x, rw, ebias, topk, gating, zacc);
    rank_kernel<<<ENUM, 256, 0, stream>>>(topk, slot2tok, gmap);

    // conversions (small, persistent)
    convert_kernel<<<1024, 256, 0, stream>>>(x, xb, (long long)NTOK * DMODEL);
    convert_kernel<<<256, 256, 0, stream>>>(w_down, wdownb, (long long)BND * DMODEL);
    convert_kernel<<<256, 256, 0, stream>>>(w_up, wupb, (long long)DMODEL * BND);

    // hd = x @ w_down^T  (bf16, with zero row at NTOK)
    gemm2<0, 0><<<dim3(BND / 128, NTOK / 128, 1), 256, 0, stream>>>(
        xb, 0, DMODEL, nullptr, wdownb, 0, DMODEL, hd, 0, BND, NTOK, DMODEL);

    // shared MLP: H1 = x@gate^T ; H1 = silu(H1) * (x@up^T) ; out = H1 @ down^T
    convert_kernel<<<1024, 256, 0, stream>>>(gate_w, wbuf, (long long)HSH * DMODEL);
    gemm2<0, 0><<<dim3(HSH / 128, NTOK / 128, 1), 256, 0, stream>>>(
        xb, 0, DMODEL, nullptr, wbuf, 0, DMODEL, H1, 0, HSH, NTOK, DMODEL);
    convert_kernel<<<1024, 256, 0, stream>>>(up_w, wbuf, (long long)HSH * DMODEL);
    gemm2<0, 1><<<dim3(HSH / 128, NTOK / 128, 1), 256, 0, stream>>>(
        xb, 0, DMODEL, nullptr, wbuf, 0, DMODEL, H1, 0, HSH, NTOK, DMODEL);
    convert_kernel<<<1024, 256, 0, stream>>>(down_w, wbuf, (long long)DMODEL * HSH);
    gemm2<0, 2><<<dim3(DMODEL / 128, NTOK / 128, 1), 256, 0, stream>>>(
        H1, 0, HSH, nullptr, wbuf, 0, HSH, out, 0, DMODEL, NTOK, HSH);

    // expert path, 16 experts per chunk (wbuf + H1-arena reuse)
    for (int c = 0; c < ENUM / ECH; c++) {
        tconv_kernel<<<dim3(2048 / 32, 512 / 32, ECH), 256, 0, stream>>>(
            w12 + (size_t)c * ECH * 512 * 2048, wbuf, 512, 2048);
        gemm2<1, 0><<<dim3(2048 / 128, 3, ECH), 256, 0, stream>>>(
            hd, 0, BND, slot2tok + (size_t)c * ECH * MAXL,
            wbuf, (long long)2048 * 512, 512,
            h12, (long long)EPAD * 2048, 2048, MAXL, BND);
        tconv_kernel<<<dim3(512 / 32, 1024 / 32, ECH), 256, 0, stream>>>(
            w3 + (size_t)c * ECH * 1024 * 512, wbuf, 1024, 512);
        siluact_kernel<<<dim3(EPAD, ECH), 256, 0, stream>>>(h12, act);
        gemm2<0, 0><<<dim3(BND / 128, 3, ECH), 256, 0, stream>>>(
            act, (long long)EPAD * FEXP, FEXP, nullptr,
            wbuf, (long long)BND * FEXP, FEXP,
            pout + (size_t)c * ECH * MAXL * BND, (long long)MAXL * BND, BND, MAXL, FEXP);
    }

    gather_kernel<<<NTOK, 256, 0, stream>>>(pout, gmap, gating, rb);

    // routed = rb @ w_up^T ; out = (shared + routed) * 0.5
    gemm2<0, 3><<<dim3(DMODEL / 128, NTOK / 128, 1), 256, 0, stream>>>(
        rb, 0, BND, nullptr, wupb, 0, BND, out, 0, DMODEL, NTOK, BND);

    zloss_kernel<<<1, 1, 0, stream>>>(zacc, out + (size_t)NTOK * DMODEL);
}

// Round 4
// 1281.546 us; speedup vs baseline: 1.9875x; 1.0468x over previous
//
#include <hip/hip_runtime.h>
#include <math.h>

#define NTOK 4096
#define DMODEL 2048
#define ENUM 64
#define HSH 8192
#define BND 512
#define FEXP 1024
#define MAXL 304   // (16384/64/8 + 6)*8
#define EPAD 384   // padded expert rows (3*128)
#define ECH 16     // experts per chunk

typedef float f32x4 __attribute__((ext_vector_type(4)));
using bf16x8 = __attribute__((ext_vector_type(8))) __bf16;

typedef const __attribute__((address_space(1))) unsigned int cgu32;
typedef __attribute__((address_space(3))) unsigned int lu32;
#define GLOAD16(g, l) __builtin_amdgcn_global_load_lds((cgu32*)(g), (lu32*)(l), 16, 0, 0)

__device__ __forceinline__ unsigned short f2bf(float f) {
    union { float f; unsigned int u; } v; v.f = f;
    unsigned int u = v.u;
    return (unsigned short)((u + 0x7FFFu + ((u >> 16) & 1u)) >> 16);
}
__device__ __forceinline__ float bf2f(unsigned short s) {
    union { unsigned int u; float f; } v; v.u = ((unsigned int)s) << 16;
    return v.f;
}

// ---------------- init ----------------
__global__ __launch_bounds__(256) void init_kernel(float* zacc, int* slot2tok, unsigned short* hdz) {
    int i = blockIdx.x * 256 + threadIdx.x;
    if (i == 0) *zacc = 0.f;
    if (i < ENUM * MAXL) slot2tok[i] = NTOK;  // sentinel -> zero row of hd
    if (i < BND) hdz[i] = 0;                  // hd row NTOK = zeros
}

// ---------------- fp32 -> bf16 convert ----------------
__global__ __launch_bounds__(256) void convert_kernel(
    const float* __restrict__ in, unsigned short* __restrict__ out, long long n)
{
    long long stride = (long long)gridDim.x * 256 * 8;
    for (long long i = ((long long)blockIdx.x * 256 + threadIdx.x) * 8; i < n; i += stride) {
        float4 a = *(const float4*)(in + i);
        float4 b = *(const float4*)(in + i + 4);
        union { unsigned short s[8]; uint4 v; } o;
        o.s[0] = f2bf(a.x); o.s[1] = f2bf(a.y); o.s[2] = f2bf(a.z); o.s[3] = f2bf(a.w);
        o.s[4] = f2bf(b.x); o.s[5] = f2bf(b.y); o.s[6] = f2bf(b.z); o.s[7] = f2bf(b.w);
        *(uint4*)(out + i) = o.v;
    }
}

// ---------------- transpose-convert: in [K][N] fp32 -> out [N][K] bf16 (per z) ----------------
__global__ __launch_bounds__(256) void tconv_kernel(
    const float* __restrict__ in, unsigned short* __restrict__ out, int Kd, int Nd)
{
    __shared__ float t[32][33];
    size_t zoff = (size_t)blockIdx.z * Kd * Nd;
    in += zoff; out += zoff;
    int n0 = blockIdx.x * 32, k0 = blockIdx.y * 32;
    int r = threadIdx.x >> 3, c = (threadIdx.x & 7) * 4;
    float4 v = *(const float4*)(in + (size_t)(k0 + r) * Nd + n0 + c);
    t[r][c] = v.x; t[r][c + 1] = v.y; t[r][c + 2] = v.z; t[r][c + 3] = v.w;
    __syncthreads();
    ushort4 o;
    o.x = f2bf(t[c + 0][r]); o.y = f2bf(t[c + 1][r]);
    o.z = f2bf(t[c + 2][r]); o.w = f2bf(t[c + 3][r]);
    *(ushort4*)(out + (size_t)(n0 + r) * Kd + k0 + c) = o;
}

// ---------------- router: fp32 logits, top-4, gating, z_loss ----------------
__global__ __launch_bounds__(256) void router_kernel(
    const float* __restrict__ x, const float* __restrict__ rw,
    const float* __restrict__ bias, int* __restrict__ topk_idx,
    float* __restrict__ gating, float* __restrict__ zacc)
{
    int n = blockIdx.x;
    __shared__ float hrow[DMODEL];
    __shared__ float partial[ENUM][4];
    const float* hx = x + (size_t)n * DMODEL;
    for (int i = threadIdx.x; i < DMODEL; i += 256) hrow[i] = hx[i];
    __syncthreads();
    int e = threadIdx.x & 63;
    int p = threadIdx.x >> 6;
    const float4* wr4 = (const float4*)(rw + (size_t)e * DMODEL + p * 512);
    const float4* h4 = (const float4*)(hrow + p * 512);
    float s = 0.f;
    for (int i = 0; i < 128; i++) {
        float4 a = h4[i]; float4 b = wr4[i];
        s += a.x * b.x + a.y * b.y + a.z * b.z + a.w * b.w;
    }
    partial[e][p] = s;
    __syncthreads();
    if (threadIdx.x < 64) {
        float logit = partial[e][0] + partial[e][1] + partial[e][2] + partial[e][3];
        float sel = 1.f / (1.f + expf(-logit)) + bias[e];
        float zsq = logit * logit;
        for (int off = 32; off; off >>= 1) zsq += __shfl_down(zsq, off);
        if (e == 0) atomicAdd(zacc, zsq);
        float cur = sel;
        float ch_logit[4]; int ch_idx[4];
        for (int kk = 0; kk < 4; kk++) {
            float v = cur; int idx = e;
            for (int off = 1; off < 64; off <<= 1) {
                float v2 = __shfl_xor(v, off);
                int i2 = __shfl_xor(idx, off);
                if (v2 > v || (v2 == v && i2 < idx)) { v = v2; idx = i2; }
            }
            ch_idx[kk] = idx;
            ch_logit[kk] = __shfl(logit, idx);
            if (e == idx) cur = -1e30f;
        }
        if (e == 0) {
            float mx = ch_logit[0];
            for (int kk = 1; kk < 4; kk++) mx = fmaxf(mx, ch_logit[kk]);
            float se = 0.f, ex[4];
            for (int kk = 0; kk < 4; kk++) { ex[kk] = expf(ch_logit[kk] - mx); se += ex[kk]; }
            for (int kk = 0; kk < 4; kk++) {
                topk_idx[n * 4 + kk] = ch_idx[kk];
                gating[n * 4 + kk] = ex[kk] / se;
            }
        }
    }
}

// ---------------- stable per-expert ranks ----------------
__global__ __launch_bounds__(256) void rank_kernel(
    const int* __restrict__ topk_idx, int* __restrict__ slot2tok, int* __restrict__ gmap)
{
    int e = blockIdx.x;
    __shared__ int wsum[4];
    int tid = threadIdx.x;
    int lane = tid & 63, w = tid >> 6;
    int running = 0;
    for (int c = 0; c < NTOK * 4; c += 256) {
        int i = c + tid;
        int fl = topk_idx[i];
        bool m = (fl == e);
        unsigned long long bal = __ballot(m);
        int prefix = __popcll(bal & ((1ULL << lane) - 1ULL));
        if (lane == 0) wsum[w] = __popcll(bal);
        __syncthreads();
        int wbase = 0;
        for (int j = 0; j < w; j++) wbase += wsum[j];
        int total = wsum[0] + wsum[1] + wsum[2] + wsum[3];
        if (m) {
            int rank = running + wbase + prefix;
            int tok = i >> 2;
            if (rank < MAXL) {
                slot2tok[e * MAXL + rank] = tok;
                gmap[i] = e * MAXL + rank;
            } else gmap[i] = -1;
        }
        running += total;
        __syncthreads();
    }
}

// ---------------- 2-phase double-buffered bf16 GEMM (T3 minimum recipe) ----------------
// C[M][N](z) = A[M][K](z) * B[N][K](z)^T ; 128x128x64 tile, 4 waves, gload_lds + XOR swizzle
// GATHER: A row r -> hd[slot2tok[z*MAXL+r]] (sentinel NTOK = zero row)
// EPI: 0 = store bf16 ; 1 = C = silu(C)*acc bf16 (in-place RMW) ; 2 = store f32 ; 3 = f32 (prev+acc)*0.5
template<int GATHER, int EPI>
__global__ __launch_bounds__(256) void gemm2(
    const unsigned short* __restrict__ A, long long aZ, int lda,
    const int* __restrict__ gtab,
    const unsigned short* __restrict__ Bm, long long bZ, int ldb,
    void* __restrict__ Cb, long long cZ, int ldc,
    int M, int K)
{
    __shared__ unsigned short As[2][128 * 64];
    __shared__ unsigned short Bs[2][128 * 64];
    const int z = blockIdx.z;
    const int m0 = blockIdx.y * 128;
    const int n0 = blockIdx.x * 128;
    const int tid = threadIdx.x;
    const int lane = tid & 63;
    const int w = tid >> 6;
    const int wm = (w >> 1) * 64;
    const int wn = (w & 1) * 64;

    const unsigned short* Ab = A + (GATHER ? (size_t)0 : (size_t)z * aZ);
    const unsigned short* Bb = Bm + (size_t)z * bZ;

    // staging: 4 units x 16B per thread per tile; LDS dest linear, source pre-swizzled
    size_t asrc[4], bsrc[4];
    int ldso[4];
#pragma unroll
    for (int i = 0; i < 4; i++) {
        int u = i * 256 + tid;
        int r = u >> 3;                       // tile row 0..127
        int ce = ((u & 7) ^ (r & 7)) * 8;     // swizzled element col (0..56)
        ldso[i] = u * 8;
        if constexpr (GATHER) {
            int mr = m0 + r;
            int tok = (mr < M) ? gtab[(size_t)z * MAXL + mr] : NTOK;
            asrc[i] = (size_t)tok * lda + ce;
        } else {
            asrc[i] = (size_t)(m0 + r) * lda + ce;
        }
        bsrc[i] = (size_t)(n0 + r) * ldb + ce;
    }

    const int lrow = lane & 15;
    const int kg = lane >> 4;
    const int mk = (lrow & 7) << 4;           // row-XOR mask (bytes)
    int arx[4], brx[4];
#pragma unroll
    for (int t = 0; t < 4; t++) {
        arx[t] = (wm + t * 16 + lrow) * 128;
        brx[t] = (wn + t * 16 + lrow) * 128;
    }

    f32x4 acc[4][4];
#pragma unroll
    for (int a = 0; a < 4; a++)
#pragma unroll
        for (int b = 0; b < 4; b++) acc[a][b] = (f32x4)0.f;

    // prologue: stage K-tile 0 into buf 0
#pragma unroll
    for (int i = 0; i < 4; i++) GLOAD16(Ab + asrc[i], &As[0][ldso[i]]);
#pragma unroll
    for (int i = 0; i < 4; i++) GLOAD16(Bb + bsrc[i], &Bs[0][ldso[i]]);
    __syncthreads();   // drains vmcnt(0): tile 0 landed

    int cur = 0;
    for (int k0 = 0; k0 < K; k0 += 64) {
        // issue next-tile loads into the other buffer BEFORE compute
        const int kn = k0 + 64;
        if (kn < K) {
            const int nxt = cur ^ 1;
#pragma unroll
            for (int i = 0; i < 4; i++) GLOAD16(Ab + asrc[i] + kn, &As[nxt][ldso[i]]);
#pragma unroll
            for (int i = 0; i < 4; i++) GLOAD16(Bb + bsrc[i] + kn, &Bs[nxt][ldso[i]]);
        }
        const char* Abase = (const char*)&As[cur][0];
        const char* Bbase = (const char*)&Bs[cur][0];
#pragma unroll
        for (int ks = 0; ks < 2; ks++) {
            const int cb = (ks * 64 + kg * 16) ^ mk;
            bf16x8 a[4], b[4];
#pragma unroll
            for (int t = 0; t < 4; t++) {
                a[t] = *(const bf16x8*)(Abase + arx[t] + cb);
                b[t] = *(const bf16x8*)(Bbase + brx[t] + cb);
            }
#pragma unroll
            for (int ni = 0; ni < 4; ni++)
#pragma unroll
                for (int mi = 0; mi < 4; mi++)
                    acc[mi][ni] = __builtin_amdgcn_mfma_f32_16x16x32_bf16(a[mi], b[ni], acc[mi][ni], 0, 0, 0);
        }
        __syncthreads();   // drains vmcnt(0) (next tile landed) + all reads of cur done
        cur ^= 1;
    }

    const int rb0 = m0 + wm + (kg << 2);
#pragma unroll
    for (int mi = 0; mi < 4; mi++)
#pragma unroll
        for (int ni = 0; ni < 4; ni++) {
            int col = n0 + wn + ni * 16 + lrow;
#pragma unroll
            for (int r = 0; r < 4; r++) {
                int row = rb0 + mi * 16 + r;
                if (row < M) {
                    size_t ci = (size_t)z * cZ + (size_t)row * ldc + col;
                    float v = acc[mi][ni][r];
                    if constexpr (EPI == 0) {
                        ((unsigned short*)Cb)[ci] = f2bf(v);
                    } else if constexpr (EPI == 1) {
                        unsigned short* cp = (unsigned short*)Cb + ci;
                        float g = bf2f(*cp);
                        *cp = f2bf(g / (1.f + expf(-g)) * v);
                    } else if constexpr (EPI == 2) {
                        ((float*)Cb)[ci] = v;
                    } else {
                        float* cp = (float*)Cb + ci;
                        *cp = (*cp + v) * 0.5f;
                    }
                }
            }
        }
}

// ---------------- silu-mul: act = silu(h12[:,:1024]) * h12[:,1024:] ----------------
__global__ __launch_bounds__(256) void siluact_kernel(
    const unsigned short* __restrict__ h12, unsigned short* __restrict__ act)
{
    int e = blockIdx.y, m = blockIdx.x;
    const unsigned short* hr = h12 + ((size_t)e * EPAD + m) * 2048;
    unsigned short* ar = act + ((size_t)e * EPAD + m) * 1024;
    int j = threadIdx.x * 4;
    ushort4 h1 = *(const ushort4*)(hr + j);
    ushort4 h2 = *(const ushort4*)(hr + 1024 + j);
    ushort4 o;
    float v;
    v = bf2f(h1.x); o.x = f2bf(v / (1.f + expf(-v)) * bf2f(h2.x));
    v = bf2f(h1.y); o.y = f2bf(v / (1.f + expf(-v)) * bf2f(h2.y));
    v = bf2f(h1.z); o.z = f2bf(v / (1.f + expf(-v)) * bf2f(h2.z));
    v = bf2f(h1.w); o.w = f2bf(v / (1.f + expf(-v)) * bf2f(h2.w));
    *(ushort4*)(ar + j) = o;
}

// ---------------- gather + gating combine ----------------
__global__ __launch_bounds__(256) void gather_kernel(
    const unsigned short* __restrict__ pout, const int* __restrict__ gmap,
    const float* __restrict__ gating, unsigned short* __restrict__ routed_b)
{
    int n = blockIdx.x;
    int j = threadIdx.x * 2;
    float a0 = 0.f, a1 = 0.f;
#pragma unroll
    for (int kk = 0; kk < 4; kk++) {
        int slot = gmap[n * 4 + kk];
        float g = gating[n * 4 + kk];
        if (slot >= 0) {
            const unsigned short* pr = pout + (size_t)slot * BND + j;
            a0 += g * bf2f(pr[0]);
            a1 += g * bf2f(pr[1]);
        }
    }
    routed_b[(size_t)n * BND + j] = f2bf(a0);
    routed_b[(size_t)n * BND + j + 1] = f2bf(a1);
}

__global__ void zloss_kernel(const float* zacc, float* out) {
    out[0] = zacc[0] * (1.0e-4f / (float)(NTOK * ENUM));
}

// ---------------- host ----------------
extern "C" void kernel_launch(void* const* d_in, const int* in_sizes, int n_in,
                              void* d_out, int out_size, void* d_ws, size_t ws_size,
                              hipStream_t stream)
{
    const float* x      = (const float*)d_in[0];
    const float* ebias  = (const float*)d_in[1];
    const float* rw     = (const float*)d_in[2];
    const float* gate_w = (const float*)d_in[3];
    const float* up_w   = (const float*)d_in[4];
    const float* down_w = (const float*)d_in[5];
    const float* w_down = (const float*)d_in[6];
    const float* w_up   = (const float*)d_in[7];
    const float* w12    = (const float*)d_in[8];
    const float* w3     = (const float*)d_in[9];
    float* out = (float*)d_out;

    char* ws = (char*)d_ws;
    size_t off = 0;
    auto alloc = [&](size_t b) { size_t o = off; off += (b + 255) & ~(size_t)255; return o; };
    float* zacc     = (float*)(ws + alloc(4));
    int*   topk     = (int*)(ws + alloc((size_t)NTOK * 4 * 4));
    float* gating   = (float*)(ws + alloc((size_t)NTOK * 4 * 4));
    int*   gmap     = (int*)(ws + alloc((size_t)NTOK * 4 * 4));
    int*   slot2tok = (int*)(ws + alloc((size_t)ENUM * MAXL * 4));
    unsigned short* xb     = (unsigned short*)(ws + alloc((size_t)NTOK * DMODEL * 2));
    unsigned short* hd     = (unsigned short*)(ws + alloc((size_t)(NTOK + 1) * BND * 2));
    unsigned short* rb     = (unsigned short*)(ws + alloc((size_t)NTOK * BND * 2));
    unsigned short* wdownb = (unsigned short*)(ws + alloc((size_t)BND * DMODEL * 2));
    unsigned short* wupb   = (unsigned short*)(ws + alloc((size_t)DMODEL * BND * 2));
    unsigned short* wbuf   = (unsigned short*)(ws + alloc((size_t)HSH * DMODEL * 2)); // 33.55MB
    unsigned short* H1     = (unsigned short*)(ws + alloc((size_t)NTOK * HSH * 2));   // 67.1MB arena
    // expert-phase aliases inside H1 arena:
    unsigned short* h12  = H1;
    unsigned short* act  = H1 + (size_t)ECH * EPAD * 2048;
    unsigned short* pout = H1 + (size_t)ECH * EPAD * 2048 + (size_t)ECH * EPAD * 1024;

    init_kernel<<<(ENUM * MAXL + 255) / 256, 256, 0, stream>>>(zacc, slot2tok, hd + (size_t)NTOK * BND);
    router_kernel<<<NTOK, 256, 0, stream>>>(x, rw, ebias, topk, gating, zacc);
    rank_kernel<<<ENUM, 256, 0, stream>>>(topk, slot2tok, gmap);

    // conversions (small, persistent)
    convert_kernel<<<1024, 256, 0, stream>>>(x, xb, (long long)NTOK * DMODEL);
    convert_kernel<<<256, 256, 0, stream>>>(w_down, wdownb, (long long)BND * DMODEL);
    convert_kernel<<<256, 256, 0, stream>>>(w_up, wupb, (long long)DMODEL * BND);

    // hd = x @ w_down^T  (bf16, with zero row at NTOK)
    gemm2<0, 0><<<dim3(BND / 128, NTOK / 128, 1), 256, 0, stream>>>(
        xb, 0, DMODEL, nullptr, wdownb, 0, DMODEL, hd, 0, BND, NTOK, DMODEL);

    // shared MLP: H1 = x@gate^T ; H1 = silu(H1) * (x@up^T) ; out = H1 @ down^T
    convert_kernel<<<1024, 256, 0, stream>>>(gate_w, wbuf, (long long)HSH * DMODEL);
    gemm2<0, 0><<<dim3(HSH / 128, NTOK / 128, 1), 256, 0, stream>>>(
        xb, 0, DMODEL, nullptr, wbuf, 0, DMODEL, H1, 0, HSH, NTOK, DMODEL);
    convert_kernel<<<1024, 256, 0, stream>>>(up_w, wbuf, (long long)HSH * DMODEL);
    gemm2<0, 1><<<dim3(HSH / 128, NTOK / 128, 1), 256, 0, stream>>>(
        xb, 0, DMODEL, nullptr, wbuf, 0, DMODEL, H1, 0, HSH, NTOK, DMODEL);
    convert_kernel<<<1024, 256, 0, stream>>>(down_w, wbuf, (long long)DMODEL * HSH);
    gemm2<0, 2><<<dim3(DMODEL / 128, NTOK / 128, 1), 256, 0, stream>>>(
        H1, 0, HSH, nullptr, wbuf, 0, HSH, out, 0, DMODEL, NTOK, HSH);

    // expert path, 16 experts per chunk (wbuf + H1-arena reuse)
    for (int c = 0; c < ENUM / ECH; c++) {
        tconv_kernel<<<dim3(2048 / 32, 512 / 32, ECH), 256, 0, stream>>>(
            w12 + (size_t)c * ECH * 512 * 2048, wbuf, 512, 2048);
        gemm2<1, 0><<<dim3(2048 / 128, 3, ECH), 256, 0, stream>>>(
            hd, 0, BND, slot2tok + (size_t)c * ECH * MAXL,
            wbuf, (long long)2048 * 512, 512,
            h12, (long long)EPAD * 2048, 2048, MAXL, BND);
        tconv_kernel<<<dim3(512 / 32, 1024 / 32, ECH), 256, 0, stream>>>(
            w3 + (size_t)c * ECH * 1024 * 512, wbuf, 1024, 512);
        siluact_kernel<<<dim3(EPAD, ECH), 256, 0, stream>>>(h12, act);
        gemm2<0, 0><<<dim3(BND / 128, 3, ECH), 256, 0, stream>>>(
            act, (long long)EPAD * FEXP, FEXP, nullptr,
            wbuf, (long long)BND * FEXP, FEXP,
            pout + (size_t)c * ECH * MAXL * BND, (long long)MAXL * BND, BND, MAXL, FEXP);
    }

    gather_kernel<<<NTOK, 256, 0, stream>>>(pout, gmap, gating, rb);

    // routed = rb @ w_up^T ; out = (shared + routed) * 0.5
    gemm2<0, 3><<<dim3(DMODEL / 128, NTOK / 128, 1), 256, 0, stream>>>(
        rb, 0, BND, nullptr, wupb, 0, BND, out, 0, DMODEL, NTOK, BND);

    zloss_kernel<<<1, 1, 0, stream>>>(zacc, out + (size_t)NTOK * DMODEL);
}

// Round 5
// 1112.181 us; speedup vs baseline: 2.2902x; 1.1523x over previous
//
#include <hip/hip_runtime.h>
#include <math.h>

#define NTOK 4096
#define DMODEL 2048
#define ENUM 64
#define HSH 8192
#define BND 512
#define FEXP 1024
#define MAXL 304   // (16384/64/8 + 6)*8
#define EPAD 384   // padded expert rows (3*128)
#define ECH 16     // experts per chunk

typedef float f32x4 __attribute__((ext_vector_type(4)));
using bf16x8 = __attribute__((ext_vector_type(8))) __bf16;

typedef const __attribute__((address_space(1))) unsigned int cgu32;
typedef __attribute__((address_space(3))) unsigned int lu32;
#define GLOAD16(g, l) __builtin_amdgcn_global_load_lds((cgu32*)(g), (lu32*)(l), 16, 0, 0)

__device__ __forceinline__ unsigned short f2bf(float f) {
    union { float f; unsigned int u; } v; v.f = f;
    unsigned int u = v.u;
    return (unsigned short)((u + 0x7FFFu + ((u >> 16) & 1u)) >> 16);
}
__device__ __forceinline__ float bf2f(unsigned short s) {
    union { unsigned int u; float f; } v; v.u = ((unsigned int)s) << 16;
    return v.f;
}

// ---------------- init ----------------
__global__ __launch_bounds__(256) void init_kernel(float* zacc, int* slot2tok, unsigned short* hdz) {
    int i = blockIdx.x * 256 + threadIdx.x;
    if (i == 0) *zacc = 0.f;
    if (i < ENUM * MAXL) slot2tok[i] = NTOK;  // sentinel -> zero row of hd
    if (i < BND) hdz[i] = 0;                  // hd row NTOK = zeros
}

// ---------------- fp32 -> bf16 convert ----------------
__global__ __launch_bounds__(256) void convert_kernel(
    const float* __restrict__ in, unsigned short* __restrict__ out, long long n)
{
    long long stride = (long long)gridDim.x * 256 * 8;
    for (long long i = ((long long)blockIdx.x * 256 + threadIdx.x) * 8; i < n; i += stride) {
        float4 a = *(const float4*)(in + i);
        float4 b = *(const float4*)(in + i + 4);
        union { unsigned short s[8]; uint4 v; } o;
        o.s[0] = f2bf(a.x); o.s[1] = f2bf(a.y); o.s[2] = f2bf(a.z); o.s[3] = f2bf(a.w);
        o.s[4] = f2bf(b.x); o.s[5] = f2bf(b.y); o.s[6] = f2bf(b.z); o.s[7] = f2bf(b.w);
        *(uint4*)(out + i) = o.v;
    }
}

// ---------------- fp32 -> bf16 hi+lo split (for exact-ish router) ----------------
__global__ __launch_bounds__(256) void convert_x_kernel(
    const float* __restrict__ in, unsigned short* __restrict__ hi,
    unsigned short* __restrict__ lo, long long n)
{
    long long stride = (long long)gridDim.x * 256 * 8;
    for (long long i = ((long long)blockIdx.x * 256 + threadIdx.x) * 8; i < n; i += stride) {
        float4 a = *(const float4*)(in + i);
        float4 b = *(const float4*)(in + i + 4);
        union { unsigned short s[8]; uint4 v; } oh, ol;
        float f[8] = {a.x, a.y, a.z, a.w, b.x, b.y, b.z, b.w};
#pragma unroll
        for (int j = 0; j < 8; j++) {
            unsigned short h = f2bf(f[j]);
            oh.s[j] = h;
            ol.s[j] = f2bf(f[j] - bf2f(h));
        }
        *(uint4*)(hi + i) = oh.v;
        *(uint4*)(lo + i) = ol.v;
    }
}

// router weights: [64][2048] fp32 -> [128][2048] bf16 hi & lo (rows 64..127 zero)
__global__ __launch_bounds__(256) void convert_rw_kernel(
    const float* __restrict__ rw, unsigned short* __restrict__ whi,
    unsigned short* __restrict__ wlo)
{
    int i = (blockIdx.x * 256 + threadIdx.x) * 4;
    if (i >= 128 * 2048) return;
    ushort4 oh = {0, 0, 0, 0}, ol = {0, 0, 0, 0};
    if (i < 64 * 2048) {
        float4 f = *(const float4*)(rw + i);
        float v[4] = {f.x, f.y, f.z, f.w};
        unsigned short h;
        h = f2bf(v[0]); oh.x = h; ol.x = f2bf(v[0] - bf2f(h));
        h = f2bf(v[1]); oh.y = h; ol.y = f2bf(v[1] - bf2f(h));
        h = f2bf(v[2]); oh.z = h; ol.z = f2bf(v[2] - bf2f(h));
        h = f2bf(v[3]); oh.w = h; ol.w = f2bf(v[3] - bf2f(h));
    }
    *(ushort4*)(whi + i) = oh;
    *(ushort4*)(wlo + i) = ol;
}

// ---------------- transpose-convert: in [K][N] fp32 -> out [N][K] bf16 (per z) ----------------
__global__ __launch_bounds__(256) void tconv_kernel(
    const float* __restrict__ in, unsigned short* __restrict__ out, int Kd, int Nd)
{
    __shared__ float t[32][33];
    size_t zoff = (size_t)blockIdx.z * Kd * Nd;
    in += zoff; out += zoff;
    int n0 = blockIdx.x * 32, k0 = blockIdx.y * 32;
    int r = threadIdx.x >> 3, c = (threadIdx.x & 7) * 4;
    float4 v = *(const float4*)(in + (size_t)(k0 + r) * Nd + n0 + c);
    t[r][c] = v.x; t[r][c + 1] = v.y; t[r][c + 2] = v.z; t[r][c + 3] = v.w;
    __syncthreads();
    ushort4 o;
    o.x = f2bf(t[c + 0][r]); o.y = f2bf(t[c + 1][r]);
    o.z = f2bf(t[c + 2][r]); o.w = f2bf(t[c + 3][r]);
    *(ushort4*)(out + (size_t)(n0 + r) * Kd + k0 + c) = o;
}

// ---------------- router GEMM: logits[z] = A(z) @ B(z)^T, 3 terms ----------------
// z=0: x_hi @ w_hi ; z=1: x_hi @ w_lo ; z=2: x_lo @ w_hi. N=128 (cols 64+ junk/zero).
__global__ __launch_bounds__(256) void rgemm_kernel(
    const unsigned short* __restrict__ xb, const unsigned short* __restrict__ xlo,
    const unsigned short* __restrict__ whi, const unsigned short* __restrict__ wlo,
    float* __restrict__ logits)
{
    __shared__ unsigned short As[2][128 * 64];
    __shared__ unsigned short Bs[2][128 * 64];
    const int z = blockIdx.z;
    const int m0 = blockIdx.y * 128;
    const int tid = threadIdx.x;
    const int lane = tid & 63;
    const int w = tid >> 6;
    const int wm = (w >> 1) * 64;
    const int wn = (w & 1) * 64;

    const unsigned short* Ab = (z == 2) ? xlo : xb;
    const unsigned short* Bb = (z == 1) ? wlo : whi;
    float* Cb = logits + (size_t)z * NTOK * 128;

    size_t asrc[4], bsrc[4];
    int ldso[4];
#pragma unroll
    for (int i = 0; i < 4; i++) {
        int u = i * 256 + tid;
        int r = u >> 3;
        int ce = ((u & 7) ^ (r & 7)) * 8;
        ldso[i] = u * 8;
        asrc[i] = (size_t)(m0 + r) * DMODEL + ce;
        bsrc[i] = (size_t)r * DMODEL + ce;
    }

    const int lrow = lane & 15;
    const int kg = lane >> 4;
    const int mk = (lrow & 7) << 4;
    int arx[4], brx[4];
#pragma unroll
    for (int t = 0; t < 4; t++) {
        arx[t] = (wm + t * 16 + lrow) * 128;
        brx[t] = (wn + t * 16 + lrow) * 128;
    }

    f32x4 acc[4][4];
#pragma unroll
    for (int a = 0; a < 4; a++)
#pragma unroll
        for (int b = 0; b < 4; b++) acc[a][b] = (f32x4)0.f;

#pragma unroll
    for (int i = 0; i < 4; i++) GLOAD16(Ab + asrc[i], &As[0][ldso[i]]);
#pragma unroll
    for (int i = 0; i < 4; i++) GLOAD16(Bb + bsrc[i], &Bs[0][ldso[i]]);
    __syncthreads();

    int cur = 0;
    for (int k0 = 0; k0 < DMODEL; k0 += 64) {
        const int kn = k0 + 64;
        if (kn < DMODEL) {
            const int nxt = cur ^ 1;
#pragma unroll
            for (int i = 0; i < 4; i++) GLOAD16(Ab + asrc[i] + kn, &As[nxt][ldso[i]]);
#pragma unroll
            for (int i = 0; i < 4; i++) GLOAD16(Bb + bsrc[i] + kn, &Bs[nxt][ldso[i]]);
        }
        const char* Abase = (const char*)&As[cur][0];
        const char* Bbase = (const char*)&Bs[cur][0];
#pragma unroll
        for (int ks = 0; ks < 2; ks++) {
            const int cb = (ks * 64 + kg * 16) ^ mk;
            bf16x8 a[4], b[4];
#pragma unroll
            for (int t = 0; t < 4; t++) {
                a[t] = *(const bf16x8*)(Abase + arx[t] + cb);
                b[t] = *(const bf16x8*)(Bbase + brx[t] + cb);
            }
#pragma unroll
            for (int ni = 0; ni < 4; ni++)
#pragma unroll
                for (int mi = 0; mi < 4; mi++)
                    acc[mi][ni] = __builtin_amdgcn_mfma_f32_16x16x32_bf16(a[mi], b[ni], acc[mi][ni], 0, 0, 0);
        }
        __syncthreads();
        cur ^= 1;
    }

    const int rb0 = m0 + wm + (kg << 2);
#pragma unroll
    for (int mi = 0; mi < 4; mi++)
#pragma unroll
        for (int ni = 0; ni < 4; ni++) {
            int col = wn + ni * 16 + lrow;
#pragma unroll
            for (int r = 0; r < 4; r++)
                Cb[(size_t)(rb0 + mi * 16 + r) * 128 + col] = acc[mi][ni][r];
        }
}

// ---------------- top-4 + gating + z_loss from 3-term logits ----------------
__global__ __launch_bounds__(256) void topk_kernel(
    const float* __restrict__ logits, const float* __restrict__ bias,
    int* __restrict__ topk_idx, float* __restrict__ gating, float* __restrict__ zacc)
{
    __shared__ float zpart[4];
    const size_t Z = (size_t)NTOK * 128;
    int wv = threadIdx.x >> 6, lane = threadIdx.x & 63;
    int n = blockIdx.x * 4 + wv;
    const float* lp = logits + (size_t)n * 128 + lane;
    float logit = lp[0] + lp[Z] + lp[2 * Z];
    float sel = 1.f / (1.f + expf(-logit)) + bias[lane];
    float zsq = logit * logit;
    for (int off = 32; off; off >>= 1) zsq += __shfl_down(zsq, off);
    if (lane == 0) zpart[wv] = zsq;
    __syncthreads();
    if (threadIdx.x == 0) atomicAdd(zacc, zpart[0] + zpart[1] + zpart[2] + zpart[3]);
    float cur = sel;
    float ch_logit[4]; int ch_idx[4];
    for (int kk = 0; kk < 4; kk++) {
        float v = cur; int idx = lane;
        for (int off = 1; off < 64; off <<= 1) {
            float v2 = __shfl_xor(v, off);
            int i2 = __shfl_xor(idx, off);
            if (v2 > v || (v2 == v && i2 < idx)) { v = v2; idx = i2; }
        }
        ch_idx[kk] = idx;
        ch_logit[kk] = __shfl(logit, idx);
        if (lane == idx) cur = -1e30f;
    }
    if (lane == 0) {
        float mx = ch_logit[0];
        for (int kk = 1; kk < 4; kk++) mx = fmaxf(mx, ch_logit[kk]);
        float se = 0.f, ex[4];
        for (int kk = 0; kk < 4; kk++) { ex[kk] = expf(ch_logit[kk] - mx); se += ex[kk]; }
        for (int kk = 0; kk < 4; kk++) {
            topk_idx[n * 4 + kk] = ch_idx[kk];
            gating[n * 4 + kk] = ex[kk] / se;
        }
    }
}

// ---------------- stable per-expert ranks ----------------
__global__ __launch_bounds__(256) void rank_kernel(
    const int* __restrict__ topk_idx, int* __restrict__ slot2tok, int* __restrict__ gmap)
{
    int e = blockIdx.x;
    __shared__ int wsum[4];
    int tid = threadIdx.x;
    int lane = tid & 63, w = tid >> 6;
    int running = 0;
    for (int c = 0; c < NTOK * 4; c += 256) {
        int i = c + tid;
        int fl = topk_idx[i];
        bool m = (fl == e);
        unsigned long long bal = __ballot(m);
        int prefix = __popcll(bal & ((1ULL << lane) - 1ULL));
        if (lane == 0) wsum[w] = __popcll(bal);
        __syncthreads();
        int wbase = 0;
        for (int j = 0; j < w; j++) wbase += wsum[j];
        int total = wsum[0] + wsum[1] + wsum[2] + wsum[3];
        if (m) {
            int rank = running + wbase + prefix;
            int tok = i >> 2;
            if (rank < MAXL) {
                slot2tok[e * MAXL + rank] = tok;
                gmap[i] = e * MAXL + rank;
            } else gmap[i] = -1;
        }
        running += total;
        __syncthreads();
    }
}

// ---------------- 2-phase double-buffered bf16 GEMM ----------------
template<int GATHER, int EPI>
__global__ __launch_bounds__(256) void gemm2(
    const unsigned short* __restrict__ A, long long aZ, int lda,
    const int* __restrict__ gtab,
    const unsigned short* __restrict__ Bm, long long bZ, int ldb,
    void* __restrict__ Cb, long long cZ, int ldc,
    int M, int K)
{
    __shared__ unsigned short As[2][128 * 64];
    __shared__ unsigned short Bs[2][128 * 64];
    const int z = blockIdx.z;
    const int m0 = blockIdx.y * 128;
    const int n0 = blockIdx.x * 128;
    const int tid = threadIdx.x;
    const int lane = tid & 63;
    const int w = tid >> 6;
    const int wm = (w >> 1) * 64;
    const int wn = (w & 1) * 64;

    const unsigned short* Ab = A + (GATHER ? (size_t)0 : (size_t)z * aZ);
    const unsigned short* Bb = Bm + (size_t)z * bZ;

    size_t asrc[4], bsrc[4];
    int ldso[4];
#pragma unroll
    for (int i = 0; i < 4; i++) {
        int u = i * 256 + tid;
        int r = u >> 3;
        int ce = ((u & 7) ^ (r & 7)) * 8;
        ldso[i] = u * 8;
        if constexpr (GATHER) {
            int mr = m0 + r;
            int tok = (mr < M) ? gtab[(size_t)z * MAXL + mr] : NTOK;
            asrc[i] = (size_t)tok * lda + ce;
        } else {
            asrc[i] = (size_t)(m0 + r) * lda + ce;
        }
        bsrc[i] = (size_t)(n0 + r) * ldb + ce;
    }

    const int lrow = lane & 15;
    const int kg = lane >> 4;
    const int mk = (lrow & 7) << 4;
    int arx[4], brx[4];
#pragma unroll
    for (int t = 0; t < 4; t++) {
        arx[t] = (wm + t * 16 + lrow) * 128;
        brx[t] = (wn + t * 16 + lrow) * 128;
    }

    f32x4 acc[4][4];
#pragma unroll
    for (int a = 0; a < 4; a++)
#pragma unroll
        for (int b = 0; b < 4; b++) acc[a][b] = (f32x4)0.f;

#pragma unroll
    for (int i = 0; i < 4; i++) GLOAD16(Ab + asrc[i], &As[0][ldso[i]]);
#pragma unroll
    for (int i = 0; i < 4; i++) GLOAD16(Bb + bsrc[i], &Bs[0][ldso[i]]);
    __syncthreads();

    int cur = 0;
    for (int k0 = 0; k0 < K; k0 += 64) {
        const int kn = k0 + 64;
        if (kn < K) {
            const int nxt = cur ^ 1;
#pragma unroll
            for (int i = 0; i < 4; i++) GLOAD16(Ab + asrc[i] + kn, &As[nxt][ldso[i]]);
#pragma unroll
            for (int i = 0; i < 4; i++) GLOAD16(Bb + bsrc[i] + kn, &Bs[nxt][ldso[i]]);
        }
        const char* Abase = (const char*)&As[cur][0];
        const char* Bbase = (const char*)&Bs[cur][0];
#pragma unroll
        for (int ks = 0; ks < 2; ks++) {
            const int cb = (ks * 64 + kg * 16) ^ mk;
            bf16x8 a[4], b[4];
#pragma unroll
            for (int t = 0; t < 4; t++) {
                a[t] = *(const bf16x8*)(Abase + arx[t] + cb);
                b[t] = *(const bf16x8*)(Bbase + brx[t] + cb);
            }
#pragma unroll
            for (int ni = 0; ni < 4; ni++)
#pragma unroll
                for (int mi = 0; mi < 4; mi++)
                    acc[mi][ni] = __builtin_amdgcn_mfma_f32_16x16x32_bf16(a[mi], b[ni], acc[mi][ni], 0, 0, 0);
        }
        __syncthreads();
        cur ^= 1;
    }

    const int rb0 = m0 + wm + (kg << 2);
#pragma unroll
    for (int mi = 0; mi < 4; mi++)
#pragma unroll
        for (int ni = 0; ni < 4; ni++) {
            int col = n0 + wn + ni * 16 + lrow;
#pragma unroll
            for (int r = 0; r < 4; r++) {
                int row = rb0 + mi * 16 + r;
                if (row < M) {
                    size_t ci = (size_t)z * cZ + (size_t)row * ldc + col;
                    float v = acc[mi][ni][r];
                    if constexpr (EPI == 0) {
                        ((unsigned short*)Cb)[ci] = f2bf(v);
                    } else if constexpr (EPI == 1) {
                        unsigned short* cp = (unsigned short*)Cb + ci;
                        float g = bf2f(*cp);
                        *cp = f2bf(g / (1.f + expf(-g)) * v);
                    } else if constexpr (EPI == 2) {
                        ((float*)Cb)[ci] = v;
                    } else {
                        float* cp = (float*)Cb + ci;
                        *cp = (*cp + v) * 0.5f;
                    }
                }
            }
        }
}

// ---------------- silu-mul: act = silu(h12[:,:1024]) * h12[:,1024:] ----------------
__global__ __launch_bounds__(256) void siluact_kernel(
    const unsigned short* __restrict__ h12, unsigned short* __restrict__ act)
{
    int e = blockIdx.y, m = blockIdx.x;
    const unsigned short* hr = h12 + ((size_t)e * EPAD + m) * 2048;
    unsigned short* ar = act + ((size_t)e * EPAD + m) * 1024;
    int j = threadIdx.x * 4;
    ushort4 h1 = *(const ushort4*)(hr + j);
    ushort4 h2 = *(const ushort4*)(hr + 1024 + j);
    ushort4 o;
    float v;
    v = bf2f(h1.x); o.x = f2bf(v / (1.f + expf(-v)) * bf2f(h2.x));
    v = bf2f(h1.y); o.y = f2bf(v / (1.f + expf(-v)) * bf2f(h2.y));
    v = bf2f(h1.z); o.z = f2bf(v / (1.f + expf(-v)) * bf2f(h2.z));
    v = bf2f(h1.w); o.w = f2bf(v / (1.f + expf(-v)) * bf2f(h2.w));
    *(ushort4*)(ar + j) = o;
}

// ---------------- gather + gating combine ----------------
__global__ __launch_bounds__(256) void gather_kernel(
    const unsigned short* __restrict__ pout, const int* __restrict__ gmap,
    const float* __restrict__ gating, unsigned short* __restrict__ routed_b)
{
    int n = blockIdx.x;
    int j = threadIdx.x * 2;
    float a0 = 0.f, a1 = 0.f;
#pragma unroll
    for (int kk = 0; kk < 4; kk++) {
        int slot = gmap[n * 4 + kk];
        float g = gating[n * 4 + kk];
        if (slot >= 0) {
            const unsigned short* pr = pout + (size_t)slot * BND + j;
            a0 += g * bf2f(pr[0]);
            a1 += g * bf2f(pr[1]);
        }
    }
    routed_b[(size_t)n * BND + j] = f2bf(a0);
    routed_b[(size_t)n * BND + j + 1] = f2bf(a1);
}

__global__ void zloss_kernel(const float* zacc, float* out) {
    out[0] = zacc[0] * (1.0e-4f / (float)(NTOK * ENUM));
}

// ---------------- host ----------------
extern "C" void kernel_launch(void* const* d_in, const int* in_sizes, int n_in,
                              void* d_out, int out_size, void* d_ws, size_t ws_size,
                              hipStream_t stream)
{
    const float* x      = (const float*)d_in[0];
    const float* ebias  = (const float*)d_in[1];
    const float* rw     = (const float*)d_in[2];
    const float* gate_w = (const float*)d_in[3];
    const float* up_w   = (const float*)d_in[4];
    const float* down_w = (const float*)d_in[5];
    const float* w_down = (const float*)d_in[6];
    const float* w_up   = (const float*)d_in[7];
    const float* w12    = (const float*)d_in[8];
    const float* w3     = (const float*)d_in[9];
    float* out = (float*)d_out;

    char* ws = (char*)d_ws;
    size_t off = 0;
    auto alloc = [&](size_t b) { size_t o = off; off += (b + 255) & ~(size_t)255; return o; };
    float* zacc     = (float*)(ws + alloc(4));
    int*   topk     = (int*)(ws + alloc((size_t)NTOK * 4 * 4));
    float* gating   = (float*)(ws + alloc((size_t)NTOK * 4 * 4));
    int*   gmap     = (int*)(ws + alloc((size_t)NTOK * 4 * 4));
    int*   slot2tok = (int*)(ws + alloc((size_t)ENUM * MAXL * 4));
    unsigned short* xb     = (unsigned short*)(ws + alloc((size_t)NTOK * DMODEL * 2));
    unsigned short* hd     = (unsigned short*)(ws + alloc((size_t)(NTOK + 1) * BND * 2));
    unsigned short* rb     = (unsigned short*)(ws + alloc((size_t)NTOK * BND * 2));
    unsigned short* wdownb = (unsigned short*)(ws + alloc((size_t)BND * DMODEL * 2));
    unsigned short* wupb   = (unsigned short*)(ws + alloc((size_t)DMODEL * BND * 2));
    unsigned short* wbuf   = (unsigned short*)(ws + alloc((size_t)HSH * DMODEL * 2)); // 33.55MB
    unsigned short* H1     = (unsigned short*)(ws + alloc((size_t)NTOK * HSH * 2));   // 67.1MB arena
    // expert-phase aliases inside H1 arena:
    unsigned short* h12  = H1;
    unsigned short* act  = H1 + (size_t)ECH * EPAD * 2048;
    unsigned short* pout = H1 + (size_t)ECH * EPAD * 2048 + (size_t)ECH * EPAD * 1024;
    // router-phase aliases inside H1 arena (dead before gate GEMM writes H1):
    unsigned short* xlo    = H1;                                            // 16.78MB
    float*          logits = (float*)((char*)H1 + (size_t)NTOK * DMODEL * 2);         // 3*4096*128*4 = 6.29MB
    unsigned short* whi    = (unsigned short*)((char*)logits + (size_t)3 * NTOK * 128 * 4); // 0.52MB
    unsigned short* wlo    = whi + (size_t)128 * DMODEL;                    // 0.52MB

    init_kernel<<<(ENUM * MAXL + 255) / 256, 256, 0, stream>>>(zacc, slot2tok, hd + (size_t)NTOK * BND);

    // router: hi/lo split GEMM (3 terms) + top-k
    convert_x_kernel<<<1024, 256, 0, stream>>>(x, xb, xlo, (long long)NTOK * DMODEL);
    convert_rw_kernel<<<(128 * 2048 / 4 + 255) / 256, 256, 0, stream>>>(rw, whi, wlo);
    rgemm_kernel<<<dim3(1, NTOK / 128, 3), 256, 0, stream>>>(xb, xlo, whi, wlo, logits);
    topk_kernel<<<NTOK / 4, 256, 0, stream>>>(logits, ebias, topk, gating, zacc);
    rank_kernel<<<ENUM, 256, 0, stream>>>(topk, slot2tok, gmap);

    convert_kernel<<<256, 256, 0, stream>>>(w_down, wdownb, (long long)BND * DMODEL);
    convert_kernel<<<256, 256, 0, stream>>>(w_up, wupb, (long long)DMODEL * BND);

    // hd = x @ w_down^T  (bf16, with zero row at NTOK)
    gemm2<0, 0><<<dim3(BND / 128, NTOK / 128, 1), 256, 0, stream>>>(
        xb, 0, DMODEL, nullptr, wdownb, 0, DMODEL, hd, 0, BND, NTOK, DMODEL);

    // shared MLP: H1 = x@gate^T ; H1 = silu(H1) * (x@up^T) ; out = H1 @ down^T
    convert_kernel<<<1024, 256, 0, stream>>>(gate_w, wbuf, (long long)HSH * DMODEL);
    gemm2<0, 0><<<dim3(HSH / 128, NTOK / 128, 1), 256, 0, stream>>>(
        xb, 0, DMODEL, nullptr, wbuf, 0, DMODEL, H1, 0, HSH, NTOK, DMODEL);
    convert_kernel<<<1024, 256, 0, stream>>>(up_w, wbuf, (long long)HSH * DMODEL);
    gemm2<0, 1><<<dim3(HSH / 128, NTOK / 128, 1), 256, 0, stream>>>(
        xb, 0, DMODEL, nullptr, wbuf, 0, DMODEL, H1, 0, HSH, NTOK, DMODEL);
    convert_kernel<<<1024, 256, 0, stream>>>(down_w, wbuf, (long long)DMODEL * HSH);
    gemm2<0, 2><<<dim3(DMODEL / 128, NTOK / 128, 1), 256, 0, stream>>>(
        H1, 0, HSH, nullptr, wbuf, 0, HSH, out, 0, DMODEL, NTOK, HSH);

    // expert path, 16 experts per chunk (wbuf + H1-arena reuse)
    for (int c = 0; c < ENUM / ECH; c++) {
        tconv_kernel<<<dim3(2048 / 32, 512 / 32, ECH), 256, 0, stream>>>(
            w12 + (size_t)c * ECH * 512 * 2048, wbuf, 512, 2048);
        gemm2<1, 0><<<dim3(2048 / 128, 3, ECH), 256, 0, stream>>>(
            hd, 0, BND, slot2tok + (size_t)c * ECH * MAXL,
            wbuf, (long long)2048 * 512, 512,
            h12, (long long)EPAD * 2048, 2048, MAXL, BND);
        tconv_kernel<<<dim3(512 / 32, 1024 / 32, ECH), 256, 0, stream>>>(
            w3 + (size_t)c * ECH * 1024 * 512, wbuf, 1024, 512);
        siluact_kernel<<<dim3(EPAD, ECH), 256, 0, stream>>>(h12, act);
        gemm2<0, 0><<<dim3(BND / 128, 3, ECH), 256, 0, stream>>>(
            act, (long long)EPAD * FEXP, FEXP, nullptr,
            wbuf, (long long)BND * FEXP, FEXP,
            pout + (size_t)c * ECH * MAXL * BND, (long long)MAXL * BND, BND, MAXL, FEXP);
    }

    gather_kernel<<<NTOK, 256, 0, stream>>>(pout, gmap, gating, rb);

    // routed = rb @ w_up^T ; out = (shared + routed) * 0.5
    gemm2<0, 3><<<dim3(DMODEL / 128, NTOK / 128, 1), 256, 0, stream>>>(
        rb, 0, BND, nullptr, wupb, 0, BND, out, 0, DMODEL, NTOK, BND);

    zloss_kernel<<<1, 1, 0, stream>>>(zacc, out + (size_t)NTOK * DMODEL);
}

// Round 6
// 1097.053 us; speedup vs baseline: 2.3218x; 1.0138x over previous
//
#include <hip/hip_runtime.h>
#include <math.h>

#define NTOK 4096
#define DMODEL 2048
#define ENUM 64
#define HSH 8192
#define BND 512
#define FEXP 1024
#define MAXL 304   // (16384/64/8 + 6)*8
#define EPAD 384   // padded expert rows (3*128)
#define ECH 16     // experts per chunk

typedef float f32x4 __attribute__((ext_vector_type(4)));
using bf16x8 = __attribute__((ext_vector_type(8))) __bf16;

typedef const __attribute__((address_space(1))) unsigned int cgu32;
typedef __attribute__((address_space(3))) unsigned int lu32;
#define GLOAD16(g, l) __builtin_amdgcn_global_load_lds((cgu32*)(g), (lu32*)(l), 16, 0, 0)

__device__ __forceinline__ unsigned short f2bf(float f) {
    union { float f; unsigned int u; } v; v.f = f;
    unsigned int u = v.u;
    return (unsigned short)((u + 0x7FFFu + ((u >> 16) & 1u)) >> 16);
}
__device__ __forceinline__ float bf2f(unsigned short s) {
    union { unsigned int u; float f; } v; v.u = ((unsigned int)s) << 16;
    return v.f;
}

// ---------------- init ----------------
__global__ __launch_bounds__(256) void init_kernel(float* zacc, int* slot2tok, unsigned short* hdz) {
    int i = blockIdx.x * 256 + threadIdx.x;
    if (i == 0) *zacc = 0.f;
    if (i < ENUM * MAXL) slot2tok[i] = NTOK;  // sentinel -> zero row of hd
    if (i < BND) hdz[i] = 0;                  // hd row NTOK = zeros
}

// ---------------- fp32 -> bf16 convert ----------------
__global__ __launch_bounds__(256) void convert_kernel(
    const float* __restrict__ in, unsigned short* __restrict__ out, long long n)
{
    long long stride = (long long)gridDim.x * 256 * 8;
    for (long long i = ((long long)blockIdx.x * 256 + threadIdx.x) * 8; i < n; i += stride) {
        float4 a = *(const float4*)(in + i);
        float4 b = *(const float4*)(in + i + 4);
        union { unsigned short s[8]; uint4 v; } o;
        o.s[0] = f2bf(a.x); o.s[1] = f2bf(a.y); o.s[2] = f2bf(a.z); o.s[3] = f2bf(a.w);
        o.s[4] = f2bf(b.x); o.s[5] = f2bf(b.y); o.s[6] = f2bf(b.z); o.s[7] = f2bf(b.w);
        *(uint4*)(out + i) = o.v;
    }
}

// ---------------- fp32 -> bf16 hi+lo split (for exact-ish router) ----------------
__global__ __launch_bounds__(256) void convert_x_kernel(
    const float* __restrict__ in, unsigned short* __restrict__ hi,
    unsigned short* __restrict__ lo, long long n)
{
    long long stride = (long long)gridDim.x * 256 * 8;
    for (long long i = ((long long)blockIdx.x * 256 + threadIdx.x) * 8; i < n; i += stride) {
        float4 a = *(const float4*)(in + i);
        float4 b = *(const float4*)(in + i + 4);
        union { unsigned short s[8]; uint4 v; } oh, ol;
        float f[8] = {a.x, a.y, a.z, a.w, b.x, b.y, b.z, b.w};
#pragma unroll
        for (int j = 0; j < 8; j++) {
            unsigned short h = f2bf(f[j]);
            oh.s[j] = h;
            ol.s[j] = f2bf(f[j] - bf2f(h));
        }
        *(uint4*)(hi + i) = oh.v;
        *(uint4*)(lo + i) = ol.v;
    }
}

// router weights: [64][2048] fp32 -> [128][2048] bf16 hi & lo (rows 64..127 zero)
__global__ __launch_bounds__(256) void convert_rw_kernel(
    const float* __restrict__ rw, unsigned short* __restrict__ whi,
    unsigned short* __restrict__ wlo)
{
    int i = (blockIdx.x * 256 + threadIdx.x) * 4;
    if (i >= 128 * 2048) return;
    ushort4 oh = {0, 0, 0, 0}, ol = {0, 0, 0, 0};
    if (i < 64 * 2048) {
        float4 f = *(const float4*)(rw + i);
        float v[4] = {f.x, f.y, f.z, f.w};
        unsigned short h;
        h = f2bf(v[0]); oh.x = h; ol.x = f2bf(v[0] - bf2f(h));
        h = f2bf(v[1]); oh.y = h; ol.y = f2bf(v[1] - bf2f(h));
        h = f2bf(v[2]); oh.z = h; ol.z = f2bf(v[2] - bf2f(h));
        h = f2bf(v[3]); oh.w = h; ol.w = f2bf(v[3] - bf2f(h));
    }
    *(ushort4*)(whi + i) = oh;
    *(ushort4*)(wlo + i) = ol;
}

// ---------------- transpose-convert: in [K][N] fp32 -> out [N][K] bf16 (per z) ----------------
__global__ __launch_bounds__(256) void tconv_kernel(
    const float* __restrict__ in, unsigned short* __restrict__ out, int Kd, int Nd)
{
    __shared__ float t[32][33];
    size_t zoff = (size_t)blockIdx.z * Kd * Nd;
    in += zoff; out += zoff;
    int n0 = blockIdx.x * 32, k0 = blockIdx.y * 32;
    int r = threadIdx.x >> 3, c = (threadIdx.x & 7) * 4;
    float4 v = *(const float4*)(in + (size_t)(k0 + r) * Nd + n0 + c);
    t[r][c] = v.x; t[r][c + 1] = v.y; t[r][c + 2] = v.z; t[r][c + 3] = v.w;
    __syncthreads();
    ushort4 o;
    o.x = f2bf(t[c + 0][r]); o.y = f2bf(t[c + 1][r]);
    o.z = f2bf(t[c + 2][r]); o.w = f2bf(t[c + 3][r]);
    *(ushort4*)(out + (size_t)(n0 + r) * Kd + k0 + c) = o;
}

// ---------------- router GEMM: logits[z] = A(z) @ B(z)^T, 3 terms ----------------
__global__ __launch_bounds__(256) void rgemm_kernel(
    const unsigned short* __restrict__ xb, const unsigned short* __restrict__ xlo,
    const unsigned short* __restrict__ whi, const unsigned short* __restrict__ wlo,
    float* __restrict__ logits)
{
    __shared__ unsigned short As[2][128 * 64];
    __shared__ unsigned short Bs[2][128 * 64];
    const int z = blockIdx.z;
    const int m0 = blockIdx.y * 128;
    const int tid = threadIdx.x;
    const int lane = tid & 63;
    const int w = tid >> 6;
    const int wm = (w >> 1) * 64;
    const int wn = (w & 1) * 64;

    const unsigned short* Ab = (z == 2) ? xlo : xb;
    const unsigned short* Bb = (z == 1) ? wlo : whi;
    float* Cb = logits + (size_t)z * NTOK * 128;

    size_t asrc[4], bsrc[4];
    int ldso[4];
#pragma unroll
    for (int i = 0; i < 4; i++) {
        int u = i * 256 + tid;
        int r = u >> 3;
        int ce = ((u & 7) ^ (r & 7)) * 8;
        ldso[i] = u * 8;
        asrc[i] = (size_t)(m0 + r) * DMODEL + ce;
        bsrc[i] = (size_t)r * DMODEL + ce;
    }

    const int lrow = lane & 15;
    const int kg = lane >> 4;
    const int mk = (lrow & 7) << 4;
    int arx[4], brx[4];
#pragma unroll
    for (int t = 0; t < 4; t++) {
        arx[t] = (wm + t * 16 + lrow) * 128;
        brx[t] = (wn + t * 16 + lrow) * 128;
    }

    f32x4 acc[4][4];
#pragma unroll
    for (int a = 0; a < 4; a++)
#pragma unroll
        for (int b = 0; b < 4; b++) acc[a][b] = (f32x4)0.f;

    // prologue: stage tiles 0,1
#pragma unroll
    for (int i = 0; i < 4; i++) GLOAD16(Ab + asrc[i], &As[0][ldso[i]]);
#pragma unroll
    for (int i = 0; i < 4; i++) GLOAD16(Bb + bsrc[i], &Bs[0][ldso[i]]);
#pragma unroll
    for (int i = 0; i < 4; i++) GLOAD16(Ab + asrc[i] + 64, &As[1][ldso[i]]);
#pragma unroll
    for (int i = 0; i < 4; i++) GLOAD16(Bb + bsrc[i] + 64, &Bs[1][ldso[i]]);

    const int nt = DMODEL >> 6;
    int cur = 0;
    for (int t = 0; t < nt; ++t) {
        if (t + 1 < nt) asm volatile("s_waitcnt vmcnt(8)" ::: "memory");
        else            asm volatile("s_waitcnt vmcnt(0)" ::: "memory");
        __builtin_amdgcn_s_barrier();
        __builtin_amdgcn_sched_barrier(0);
        const char* Abase = (const char*)&As[cur][0];
        const char* Bbase = (const char*)&Bs[cur][0];
#pragma unroll
        for (int ks = 0; ks < 2; ks++) {
            const int cb = (ks * 64 + kg * 16) ^ mk;
            bf16x8 a[4], b[4];
#pragma unroll
            for (int t2 = 0; t2 < 4; t2++) {
                a[t2] = *(const bf16x8*)(Abase + arx[t2] + cb);
                b[t2] = *(const bf16x8*)(Bbase + brx[t2] + cb);
            }
#pragma unroll
            for (int ni = 0; ni < 4; ni++)
#pragma unroll
                for (int mi = 0; mi < 4; mi++)
                    acc[mi][ni] = __builtin_amdgcn_mfma_f32_16x16x32_bf16(a[mi], b[ni], acc[mi][ni], 0, 0, 0);
        }
        __builtin_amdgcn_sched_barrier(0);
        asm volatile("s_waitcnt lgkmcnt(0)" ::: "memory");
        __builtin_amdgcn_s_barrier();
        __builtin_amdgcn_sched_barrier(0);
        const int kn = (t + 2) * 64;
        if (kn < DMODEL) {
#pragma unroll
            for (int i = 0; i < 4; i++) GLOAD16(Ab + asrc[i] + kn, &As[cur][ldso[i]]);
#pragma unroll
            for (int i = 0; i < 4; i++) GLOAD16(Bb + bsrc[i] + kn, &Bs[cur][ldso[i]]);
        }
        cur ^= 1;
    }

    const int rb0 = m0 + wm + (kg << 2);
#pragma unroll
    for (int mi = 0; mi < 4; mi++)
#pragma unroll
        for (int ni = 0; ni < 4; ni++) {
            int col = wn + ni * 16 + lrow;
#pragma unroll
            for (int r = 0; r < 4; r++)
                Cb[(size_t)(rb0 + mi * 16 + r) * 128 + col] = acc[mi][ni][r];
        }
}

// ---------------- top-4 + gating + z_loss from 3-term logits ----------------
__global__ __launch_bounds__(256) void topk_kernel(
    const float* __restrict__ logits, const float* __restrict__ bias,
    int* __restrict__ topk_idx, float* __restrict__ gating, float* __restrict__ zacc)
{
    __shared__ float zpart[4];
    const size_t Z = (size_t)NTOK * 128;
    int wv = threadIdx.x >> 6, lane = threadIdx.x & 63;
    int n = blockIdx.x * 4 + wv;
    const float* lp = logits + (size_t)n * 128 + lane;
    float logit = lp[0] + lp[Z] + lp[2 * Z];
    float sel = 1.f / (1.f + expf(-logit)) + bias[lane];
    float zsq = logit * logit;
    for (int off = 32; off; off >>= 1) zsq += __shfl_down(zsq, off);
    if (lane == 0) zpart[wv] = zsq;
    __syncthreads();
    if (threadIdx.x == 0) atomicAdd(zacc, zpart[0] + zpart[1] + zpart[2] + zpart[3]);
    float cur = sel;
    float ch_logit[4]; int ch_idx[4];
    for (int kk = 0; kk < 4; kk++) {
        float v = cur; int idx = lane;
        for (int off = 1; off < 64; off <<= 1) {
            float v2 = __shfl_xor(v, off);
            int i2 = __shfl_xor(idx, off);
            if (v2 > v || (v2 == v && i2 < idx)) { v = v2; idx = i2; }
        }
        ch_idx[kk] = idx;
        ch_logit[kk] = __shfl(logit, idx);
        if (lane == idx) cur = -1e30f;
    }
    if (lane == 0) {
        float mx = ch_logit[0];
        for (int kk = 1; kk < 4; kk++) mx = fmaxf(mx, ch_logit[kk]);
        float se = 0.f, ex[4];
        for (int kk = 0; kk < 4; kk++) { ex[kk] = expf(ch_logit[kk] - mx); se += ex[kk]; }
        for (int kk = 0; kk < 4; kk++) {
            topk_idx[n * 4 + kk] = ch_idx[kk];
            gating[n * 4 + kk] = ex[kk] / se;
        }
    }
}

// ---------------- stable per-expert ranks ----------------
__global__ __launch_bounds__(256) void rank_kernel(
    const int* __restrict__ topk_idx, int* __restrict__ slot2tok, int* __restrict__ gmap)
{
    int e = blockIdx.x;
    __shared__ int wsum[4];
    int tid = threadIdx.x;
    int lane = tid & 63, w = tid >> 6;
    int running = 0;
    for (int c = 0; c < NTOK * 4; c += 256) {
        int i = c + tid;
        int fl = topk_idx[i];
        bool m = (fl == e);
        unsigned long long bal = __ballot(m);
        int prefix = __popcll(bal & ((1ULL << lane) - 1ULL));
        if (lane == 0) wsum[w] = __popcll(bal);
        __syncthreads();
        int wbase = 0;
        for (int j = 0; j < w; j++) wbase += wsum[j];
        int total = wsum[0] + wsum[1] + wsum[2] + wsum[3];
        if (m) {
            int rank = running + wbase + prefix;
            int tok = i >> 2;
            if (rank < MAXL) {
                slot2tok[e * MAXL + rank] = tok;
                gmap[i] = e * MAXL + rank;
            } else gmap[i] = -1;
        }
        running += total;
        __syncthreads();
    }
}

// ---------------- counted-vmcnt double-buffered bf16 GEMM (T3+T4) ----------------
template<int GATHER, int EPI>
__global__ __launch_bounds__(256) void gemm2(
    const unsigned short* __restrict__ A, long long aZ, int lda,
    const int* __restrict__ gtab,
    const unsigned short* __restrict__ Bm, long long bZ, int ldb,
    void* __restrict__ Cb, long long cZ, int ldc,
    int M, int K)
{
    __shared__ unsigned short As[2][128 * 64];
    __shared__ unsigned short Bs[2][128 * 64];
    const int z = blockIdx.z;
    const int m0 = blockIdx.y * 128;
    const int n0 = blockIdx.x * 128;
    const int tid = threadIdx.x;
    const int lane = tid & 63;
    const int w = tid >> 6;
    const int wm = (w >> 1) * 64;
    const int wn = (w & 1) * 64;

    const unsigned short* Ab = A + (GATHER ? (size_t)0 : (size_t)z * aZ);
    const unsigned short* Bb = Bm + (size_t)z * bZ;

    size_t asrc[4], bsrc[4];
    int ldso[4];
#pragma unroll
    for (int i = 0; i < 4; i++) {
        int u = i * 256 + tid;
        int r = u >> 3;
        int ce = ((u & 7) ^ (r & 7)) * 8;
        ldso[i] = u * 8;
        if constexpr (GATHER) {
            int mr = m0 + r;
            int tok = (mr < M) ? gtab[(size_t)z * MAXL + mr] : NTOK;
            asrc[i] = (size_t)tok * lda + ce;
        } else {
            asrc[i] = (size_t)(m0 + r) * lda + ce;
        }
        bsrc[i] = (size_t)(n0 + r) * ldb + ce;
    }

    const int lrow = lane & 15;
    const int kg = lane >> 4;
    const int mk = (lrow & 7) << 4;
    int arx[4], brx[4];
#pragma unroll
    for (int t = 0; t < 4; t++) {
        arx[t] = (wm + t * 16 + lrow) * 128;
        brx[t] = (wn + t * 16 + lrow) * 128;
    }

    f32x4 acc[4][4];
#pragma unroll
    for (int a = 0; a < 4; a++)
#pragma unroll
        for (int b = 0; b < 4; b++) acc[a][b] = (f32x4)0.f;

    // prologue: stage tiles 0 and 1
#pragma unroll
    for (int i = 0; i < 4; i++) GLOAD16(Ab + asrc[i], &As[0][ldso[i]]);
#pragma unroll
    for (int i = 0; i < 4; i++) GLOAD16(Bb + bsrc[i], &Bs[0][ldso[i]]);
    if (64 < K) {
#pragma unroll
        for (int i = 0; i < 4; i++) GLOAD16(Ab + asrc[i] + 64, &As[1][ldso[i]]);
#pragma unroll
        for (int i = 0; i < 4; i++) GLOAD16(Bb + bsrc[i] + 64, &Bs[1][ldso[i]]);
    }

    const int nt = K >> 6;
    int cur = 0;
    for (int t = 0; t < nt; ++t) {
        // own tile-t loads landed before barrier; ALL waves' tile-t loads landed after it
        if (t + 1 < nt) asm volatile("s_waitcnt vmcnt(8)" ::: "memory");
        else            asm volatile("s_waitcnt vmcnt(0)" ::: "memory");
        __builtin_amdgcn_s_barrier();
        __builtin_amdgcn_sched_barrier(0);
        const char* Abase = (const char*)&As[cur][0];
        const char* Bbase = (const char*)&Bs[cur][0];
#pragma unroll
        for (int ks = 0; ks < 2; ks++) {
            const int cb = (ks * 64 + kg * 16) ^ mk;
            bf16x8 a[4], b[4];
#pragma unroll
            for (int t2 = 0; t2 < 4; t2++) {
                a[t2] = *(const bf16x8*)(Abase + arx[t2] + cb);
                b[t2] = *(const bf16x8*)(Bbase + brx[t2] + cb);
            }
#pragma unroll
            for (int ni = 0; ni < 4; ni++)
#pragma unroll
                for (int mi = 0; mi < 4; mi++)
                    acc[mi][ni] = __builtin_amdgcn_mfma_f32_16x16x32_bf16(a[mi], b[ni], acc[mi][ni], 0, 0, 0);
        }
        __builtin_amdgcn_sched_barrier(0);
        asm volatile("s_waitcnt lgkmcnt(0)" ::: "memory");
        __builtin_amdgcn_s_barrier();   // all waves done reading buf[cur]
        __builtin_amdgcn_sched_barrier(0);
        const int kn = (t + 2) * 64;
        if (kn < K) {
#pragma unroll
            for (int i = 0; i < 4; i++) GLOAD16(Ab + asrc[i] + kn, &As[cur][ldso[i]]);
#pragma unroll
            for (int i = 0; i < 4; i++) GLOAD16(Bb + bsrc[i] + kn, &Bs[cur][ldso[i]]);
        }
        cur ^= 1;
    }

    const int rb0 = m0 + wm + (kg << 2);
#pragma unroll
    for (int mi = 0; mi < 4; mi++)
#pragma unroll
        for (int ni = 0; ni < 4; ni++) {
            int col = n0 + wn + ni * 16 + lrow;
#pragma unroll
            for (int r = 0; r < 4; r++) {
                int row = rb0 + mi * 16 + r;
                if (row < M) {
                    size_t ci = (size_t)z * cZ + (size_t)row * ldc + col;
                    float v = acc[mi][ni][r];
                    if constexpr (EPI == 0) {
                        ((unsigned short*)Cb)[ci] = f2bf(v);
                    } else if constexpr (EPI == 1) {
                        unsigned short* cp = (unsigned short*)Cb + ci;
                        float g = bf2f(*cp);
                        *cp = f2bf(g / (1.f + expf(-g)) * v);
                    } else if constexpr (EPI == 2) {
                        ((float*)Cb)[ci] = v;
                    } else {
                        float* cp = (float*)Cb + ci;
                        *cp = (*cp + v) * 0.5f;
                    }
                }
            }
        }
}

// ---------------- silu-mul: act = silu(h12[:,:1024]) * h12[:,1024:] ----------------
__global__ __launch_bounds__(256) void siluact_kernel(
    const unsigned short* __restrict__ h12, unsigned short* __restrict__ act)
{
    int e = blockIdx.y, m = blockIdx.x;
    const unsigned short* hr = h12 + ((size_t)e * EPAD + m) * 2048;
    unsigned short* ar = act + ((size_t)e * EPAD + m) * 1024;
    int j = threadIdx.x * 4;
    ushort4 h1 = *(const ushort4*)(hr + j);
    ushort4 h2 = *(const ushort4*)(hr + 1024 + j);
    ushort4 o;
    float v;
    v = bf2f(h1.x); o.x = f2bf(v / (1.f + expf(-v)) * bf2f(h2.x));
    v = bf2f(h1.y); o.y = f2bf(v / (1.f + expf(-v)) * bf2f(h2.y));
    v = bf2f(h1.z); o.z = f2bf(v / (1.f + expf(-v)) * bf2f(h2.z));
    v = bf2f(h1.w); o.w = f2bf(v / (1.f + expf(-v)) * bf2f(h2.w));
    *(ushort4*)(ar + j) = o;
}

// ---------------- gather + gating combine ----------------
__global__ __launch_bounds__(256) void gather_kernel(
    const unsigned short* __restrict__ pout, const int* __restrict__ gmap,
    const float* __restrict__ gating, unsigned short* __restrict__ routed_b)
{
    int n = blockIdx.x;
    int j = threadIdx.x * 2;
    float a0 = 0.f, a1 = 0.f;
#pragma unroll
    for (int kk = 0; kk < 4; kk++) {
        int slot = gmap[n * 4 + kk];
        float g = gating[n * 4 + kk];
        if (slot >= 0) {
            const unsigned short* pr = pout + (size_t)slot * BND + j;
            a0 += g * bf2f(pr[0]);
            a1 += g * bf2f(pr[1]);
        }
    }
    routed_b[(size_t)n * BND + j] = f2bf(a0);
    routed_b[(size_t)n * BND + j + 1] = f2bf(a1);
}

__global__ void zloss_kernel(const float* zacc, float* out) {
    out[0] = zacc[0] * (1.0e-4f / (float)(NTOK * ENUM));
}

// ---------------- host ----------------
extern "C" void kernel_launch(void* const* d_in, const int* in_sizes, int n_in,
                              void* d_out, int out_size, void* d_ws, size_t ws_size,
                              hipStream_t stream)
{
    const float* x      = (const float*)d_in[0];
    const float* ebias  = (const float*)d_in[1];
    const float* rw     = (const float*)d_in[2];
    const float* gate_w = (const float*)d_in[3];
    const float* up_w   = (const float*)d_in[4];
    const float* down_w = (const float*)d_in[5];
    const float* w_down = (const float*)d_in[6];
    const float* w_up   = (const float*)d_in[7];
    const float* w12    = (const float*)d_in[8];
    const float* w3     = (const float*)d_in[9];
    float* out = (float*)d_out;

    char* ws = (char*)d_ws;
    size_t off = 0;
    auto alloc = [&](size_t b) { size_t o = off; off += (b + 255) & ~(size_t)255; return o; };
    float* zacc     = (float*)(ws + alloc(4));
    int*   topk     = (int*)(ws + alloc((size_t)NTOK * 4 * 4));
    float* gating   = (float*)(ws + alloc((size_t)NTOK * 4 * 4));
    int*   gmap     = (int*)(ws + alloc((size_t)NTOK * 4 * 4));
    int*   slot2tok = (int*)(ws + alloc((size_t)ENUM * MAXL * 4));
    unsigned short* xb     = (unsigned short*)(ws + alloc((size_t)NTOK * DMODEL * 2));
    unsigned short* hd     = (unsigned short*)(ws + alloc((size_t)(NTOK + 1) * BND * 2));
    unsigned short* rb     = (unsigned short*)(ws + alloc((size_t)NTOK * BND * 2));
    unsigned short* wdownb = (unsigned short*)(ws + alloc((size_t)BND * DMODEL * 2));
    unsigned short* wupb   = (unsigned short*)(ws + alloc((size_t)DMODEL * BND * 2));
    unsigned short* wbuf   = (unsigned short*)(ws + alloc((size_t)HSH * DMODEL * 2)); // 33.55MB
    unsigned short* H1     = (unsigned short*)(ws + alloc((size_t)NTOK * HSH * 2));   // 67.1MB arena
    // expert-phase aliases inside H1 arena:
    unsigned short* h12  = H1;
    unsigned short* act  = H1 + (size_t)ECH * EPAD * 2048;
    unsigned short* pout = H1 + (size_t)ECH * EPAD * 2048 + (size_t)ECH * EPAD * 1024;
    // router-phase aliases inside H1 arena (dead before gate GEMM writes H1):
    unsigned short* xlo    = H1;                                            // 16.78MB
    float*          logits = (float*)((char*)H1 + (size_t)NTOK * DMODEL * 2);         // 3*4096*128*4 = 6.29MB
    unsigned short* whi    = (unsigned short*)((char*)logits + (size_t)3 * NTOK * 128 * 4); // 0.52MB
    unsigned short* wlo    = whi + (size_t)128 * DMODEL;                    // 0.52MB

    init_kernel<<<(ENUM * MAXL + 255) / 256, 256, 0, stream>>>(zacc, slot2tok, hd + (size_t)NTOK * BND);

    // router: hi/lo split GEMM (3 terms) + top-k
    convert_x_kernel<<<1024, 256, 0, stream>>>(x, xb, xlo, (long long)NTOK * DMODEL);
    convert_rw_kernel<<<(128 * 2048 / 4 + 255) / 256, 256, 0, stream>>>(rw, whi, wlo);
    rgemm_kernel<<<dim3(1, NTOK / 128, 3), 256, 0, stream>>>(xb, xlo, whi, wlo, logits);
    topk_kernel<<<NTOK / 4, 256, 0, stream>>>(logits, ebias, topk, gating, zacc);
    rank_kernel<<<ENUM, 256, 0, stream>>>(topk, slot2tok, gmap);

    convert_kernel<<<256, 256, 0, stream>>>(w_down, wdownb, (long long)BND * DMODEL);
    convert_kernel<<<256, 256, 0, stream>>>(w_up, wupb, (long long)DMODEL * BND);

    // hd = x @ w_down^T  (bf16, with zero row at NTOK)
    gemm2<0, 0><<<dim3(BND / 128, NTOK / 128, 1), 256, 0, stream>>>(
        xb, 0, DMODEL, nullptr, wdownb, 0, DMODEL, hd, 0, BND, NTOK, DMODEL);

    // shared MLP: H1 = x@gate^T ; H1 = silu(H1) * (x@up^T) ; out = H1 @ down^T
    convert_kernel<<<1024, 256, 0, stream>>>(gate_w, wbuf, (long long)HSH * DMODEL);
    gemm2<0, 0><<<dim3(HSH / 128, NTOK / 128, 1), 256, 0, stream>>>(
        xb, 0, DMODEL, nullptr, wbuf, 0, DMODEL, H1, 0, HSH, NTOK, DMODEL);
    convert_kernel<<<1024, 256, 0, stream>>>(up_w, wbuf, (long long)HSH * DMODEL);
    gemm2<0, 1><<<dim3(HSH / 128, NTOK / 128, 1), 256, 0, stream>>>(
        xb, 0, DMODEL, nullptr, wbuf, 0, DMODEL, H1, 0, HSH, NTOK, DMODEL);
    convert_kernel<<<1024, 256, 0, stream>>>(down_w, wbuf, (long long)DMODEL * HSH);
    gemm2<0, 2><<<dim3(DMODEL / 128, NTOK / 128, 1), 256, 0, stream>>>(
        H1, 0, HSH, nullptr, wbuf, 0, HSH, out, 0, DMODEL, NTOK, HSH);

    // expert path, 16 experts per chunk (wbuf + H1-arena reuse)
    for (int c = 0; c < ENUM / ECH; c++) {
        tconv_kernel<<<dim3(2048 / 32, 512 / 32, ECH), 256, 0, stream>>>(
            w12 + (size_t)c * ECH * 512 * 2048, wbuf, 512, 2048);
        gemm2<1, 0><<<dim3(2048 / 128, 3, ECH), 256, 0, stream>>>(
            hd, 0, BND, slot2tok + (size_t)c * ECH * MAXL,
            wbuf, (long long)2048 * 512, 512,
            h12, (long long)EPAD * 2048, 2048, MAXL, BND);
        tconv_kernel<<<dim3(512 / 32, 1024 / 32, ECH), 256, 0, stream>>>(
            w3 + (size_t)c * ECH * 1024 * 512, wbuf, 1024, 512);
        siluact_kernel<<<dim3(EPAD, ECH), 256, 0, stream>>>(h12, act);
        gemm2<0, 0><<<dim3(BND / 128, 3, ECH), 256, 0, stream>>>(
            act, (long long)EPAD * FEXP, FEXP, nullptr,
            wbuf, (long long)BND * FEXP, FEXP,
            pout + (size_t)c * ECH * MAXL * BND, (long long)MAXL * BND, BND, MAXL, FEXP);
    }

    gather_kernel<<<NTOK, 256, 0, stream>>>(pout, gmap, gating, rb);

    // routed = rb @ w_up^T ; out = (shared + routed) * 0.5
    gemm2<0, 3><<<dim3(DMODEL / 128, NTOK / 128, 1), 256, 0, stream>>>(
        rb, 0, BND, nullptr, wupb, 0, BND, out, 0, DMODEL, NTOK, BND);

    zloss_kernel<<<1, 1, 0, stream>>>(zacc, out + (size_t)NTOK * DMODEL);
}